// Round 19
// baseline (213.683 us; speedup 1.0000x reference)
//
#include <hip/hip_runtime.h>
#include <hip/hip_bf16.h>
#include <cstdint>

#define B 2
#define N 8192
#define KTOT 17        // self + 16 neighbors
#define CL 64
#define CEF 67         // CL + 3
#define H1 256
#define H2 128
#define CG 1024
#define O1 1024
#define O2 256
#define NCHW 8               // window chunks
#define WCH 256              // window chunk size (window = 2048)
#define KPAIR 9              // ef: 9 pairs of k-slots (17 -> 18, last duplicated)

typedef unsigned long long u64;
typedef __bf16 bf16x8 __attribute__((ext_vector_type(8)));
typedef float f32x4 __attribute__((ext_vector_type(4)));

__device__ __forceinline__ float lrelu(float v) { return fmaxf(v, 0.01f * v); }

__device__ __forceinline__ unsigned short f2bf(float f) {  // RNE
    union { float f; unsigned u; } v; v.f = f;
    unsigned r = v.u + 0x7FFFu + ((v.u >> 16) & 1u);
    return (unsigned short)(r >> 16);
}

// HW packed f32->bf16 (gfx950): low half = lo, high half = hi
__device__ __forceinline__ unsigned cvt_pk_bf16(float lo, float hi) {
    unsigned r;
    asm("v_cvt_pk_bf16_f32 %0, %1, %2" : "=v"(r) : "v"(lo), "v"(hi));
    return r;
}

__device__ __forceinline__ float norm3(float x, float y, float z) {
    return __fmaf_rn(z, z, __fmaf_rn(y, y, __fmul_rn(x, x)));
}
// d^2-scale key; MUST be byte-identical between pass1w and recover.
__device__ __forceinline__ float dist_key(float qx, float qy, float qz, float qq,
                                          float4 c) {
    float dot = __fmaf_rn(qz, c.z, __fmaf_rn(qy, c.y, __fmul_rn(qx, c.x)));
    float t = __fmaf_rn(-2.f, dot, qq);
    return fmaxf(__fadd_rn(t, c.w), 0.f);
}

__device__ __forceinline__ int nbucket(float nn) {
    return (int)fminf(nn * 16.f, 255.f);
}

// ---------------- fused: pack candidates + norm histogram ----------------
__global__ void prep_cand4_hist(const float* __restrict__ pts, float4* __restrict__ cand4,
                                unsigned* __restrict__ hist) {
    int id = blockIdx.x * 256 + threadIdx.x;       // B*N threads
    int b = id >> 13, j = id & (N - 1);
    const float* px = pts + (size_t)b * 3 * N;
    float x = px[j], y = px[N + j], z = px[2 * N + j];
    float nn = norm3(x, y, z);
    cand4[id] = make_float4(x, y, z, nn);
    atomicAdd(&hist[b * 256 + nbucket(nn)], 1u);
}

__global__ void knn_prefix(const unsigned* __restrict__ hist, unsigned* __restrict__ boff) {
    __shared__ unsigned s[256];
    int t = threadIdx.x;
    for (int b = 0; b < B; ++b) {
        s[t] = hist[b * 256 + t];
        __syncthreads();
        for (int d = 1; d < 256; d <<= 1) {
            unsigned v = (t >= d) ? s[t - d] : 0u;
            __syncthreads();
            s[t] += v;
            __syncthreads();
        }
        boff[b * 256 + t] = s[t] - hist[b * 256 + t];  // exclusive prefix
        __syncthreads();
    }
}
__global__ void knn_scatter(const float4* __restrict__ cand4, unsigned* __restrict__ boff,
                            float4* __restrict__ cand4s, int* __restrict__ sortidx) {
    int id = blockIdx.x * 256 + threadIdx.x;
    int b = id >> 13, j = id & (N - 1);
    float4 c = cand4[id];
    unsigned pos = atomicAdd(&boff[b * 256 + nbucket(c.w)], 1u);
    cand4s[(size_t)b * N + pos] = c;
    sortidx[b * N + pos] = j;
}
// NOTE: after knn_scatter, boff[b*256+k] == INCLUSIVE prefix (end of bucket k).

// ---------------- fused prepack: all 4 weight tensors in one dispatch ----------------
#define S1 24576            // ef W1 frags
#define S2 32768            // ef W2 frags
#define S3 229376           // mlp W1 frags
#define S4 262144           // mlp W2 frags
__global__ void prepack_all(const float* __restrict__ W_ef1, const float* __restrict__ W_ef2,
                            const float* __restrict__ W1, const float* __restrict__ W2,
                            unsigned short* __restrict__ W1p, unsigned short* __restrict__ W2p,
                            unsigned short* __restrict__ W1m, unsigned short* __restrict__ W2m) {
    int id = blockIdx.x * 256 + threadIdx.x;
    if (id < S1) {
        int j = id & 7, l = (id >> 3) & 63, rest = id >> 9;
        int ks = rest % 3, mt = rest / 3;
        int m = mt * 16 + (l & 15);
        int k = ks * 32 + ((l >> 4) << 3) + j;
        W1p[id] = f2bf((k < CEF) ? W_ef1[m * CEF + k] : 0.f);
        return;
    }
    id -= S1;
    if (id < S2) {
        int j = id & 7, l = (id >> 3) & 63, rest = id >> 9;
        int ks = rest & 7, mt = rest >> 3;
        int m = mt * 16 + (l & 15);
        int k = ks * 32 + ((l >> 4) << 3) + j;
        W2p[id] = f2bf(W_ef2[m * H1 + k]);
        return;
    }
    id -= S2;
    if (id < S3) {
        int j = id & 7, l = (id >> 3) & 63, rest = id >> 9;
        int ks = rest % 7; int rest2 = rest / 7;
        int mt = rest2 & 3, w = (rest2 >> 2) & 3, ch = rest2 >> 4;
        int m = ch * 256 + w * 64 + mt * 16 + (l & 15);
        int k = ks * 32 + ((l >> 4) << 3) + j;
        W1m[id] = (k < 195) ? f2bf(W1[(size_t)m * 1219 + 1024 + k]) : (unsigned short)0;
        return;
    }
    id -= S3;
    if (id < S4) {
        int j = id & 7, l = (id >> 3) & 63, rest = id >> 9;
        int ks = rest & 7; int rest2 = rest >> 3;
        int mt = rest2 & 3, w = (rest2 >> 2) & 3, ch = rest2 >> 4;
        int m = w * 64 + mt * 16 + (l & 15);
        int k = ch * 256 + ks * 32 + ((l >> 4) << 3) + j;
        W2m[id] = f2bf(W2[(size_t)m * 1024 + k]);
    }
}

// ---------------- prep lf to point-major bf16 ----------------
__global__ void prep_lf_bf(const float* __restrict__ lf, unsigned short* __restrict__ out) {
    int id = blockIdx.x * 256 + threadIdx.x;       // B*N*64 threads
    int c = id & 63;
    int n = (id >> 6) & (N - 1);
    int b = id >> 19;
    out[id] = f2bf(lf[((size_t)b * CL + c) * N + n]);
}

// ---------------- gvec: one wave per output row, shuffle reduce ----------------
__global__ __launch_bounds__(256) void gvec_kernel(const float* __restrict__ W1,
                                                   const float* __restrict__ b1,
                                                   const float* __restrict__ g,
                                                   float* __restrict__ gvec) {
    const int t = threadIdx.x;
    const int l = t & 63;
    const int o = blockIdx.x * 4 + (t >> 6);   // 0..1023
    const int b = blockIdx.y;
    const float* row = W1 + (size_t)o * 1219;
    const float* gb = g + b * CG;
    float s = 0.f;
#pragma unroll
    for (int i = 0; i < CG / 64; ++i)
        s = fmaf(row[l + i * 64], gb[l + i * 64], s);
    s += __shfl_xor(s, 1);  s += __shfl_xor(s, 2);  s += __shfl_xor(s, 4);
    s += __shfl_xor(s, 8);  s += __shfl_xor(s, 16); s += __shfl_xor(s, 32);
    if (l == 0) gvec[b * O1 + o] = s + b1[o];
}

// ---------------- KNN pass1w: top-16 over 2048 norm-window (8 chunks x 256) ----------------
__global__ __launch_bounds__(256) void knn_pass1w(const float4* __restrict__ cand4s,
                                                  float* __restrict__ topd) {
    const int t = threadIdx.x;
    const int x = blockIdx.x;       // query block (sorted positions x*256..+256)
    const int chunk = blockIdx.y;   // 0..7
    const int b = blockIdx.z;
    int wstart = x * 256 - 896;
    wstart = wstart < 0 ? 0 : (wstart > N - 2048 ? N - 2048 : wstart);
    const int p = x * 256 + t;                  // sorted position of query
    const int rel = p - wstart - chunk * WCH;   // self slot in this chunk (may be OOR)
    const float4 q = cand4s[(size_t)b * N + p];
    const float qq = q.w;
    const float4* cb = cand4s + (size_t)b * N + wstart + chunk * WCH;
    float qd[16];
#pragma unroll
    for (int r = 0; r < 16; ++r) qd[r] = __builtin_inff();
#pragma unroll 8
    for (int s = 0; s < WCH; ++s) {
        float key = dist_key(q.x, q.y, q.z, qq, cb[s]);
        if (s == rel) key = __builtin_inff();   // exclude self
#pragma unroll
        for (int r = 15; r >= 1; --r)
            qd[r] = __builtin_amdgcn_fmed3f(key, qd[r - 1], qd[r]);
        qd[0] = fminf(key, qd[0]);
    }
#pragma unroll
    for (int s = 0; s < 16; ++s)
        topd[(size_t)((b * NCHW + chunk) * 16 + s) * N + p] = qd[s];
}

// ---------------- KNN thresh: merge 8 window lists -> T' (position-indexed) ----------------
__global__ __launch_bounds__(256) void knn_thresh(const float* __restrict__ topd,
                                                  float* __restrict__ Tbuf) {
    const int t = threadIdx.x;
    const int i = blockIdx.x * 256 + t;   // sorted position
    const int b = blockIdx.y;
    float qd[16];
#pragma unroll
    for (int s = 0; s < 16; ++s)
        qd[s] = topd[(size_t)((b * NCHW + 0) * 16 + s) * N + i];
    for (int c = 1; c < NCHW; ++c) {
        for (int s = 0; s < 16; ++s) {
            float pk = topd[(size_t)((b * NCHW + c) * 16 + s) * N + i];
            if (pk >= qd[15]) break;  // sorted: rest of chunk also fails
#pragma unroll
            for (int r = 15; r >= 1; --r)
                qd[r] = __builtin_amdgcn_fmed3f(pk, qd[r - 1], qd[r]);
            qd[0] = fminf(pk, qd[0]);
        }
    }
    Tbuf[b * N + i] = qd[15];
}

// ---------------- KNN recover: norm-windowed scan (4x unrolled), exact rank-select 16 ----------------
__global__ __launch_bounds__(256) void knn_recover(const float4* __restrict__ cand4s,
                                                   const int* __restrict__ sortidx,
                                                   const float* __restrict__ Tbuf,
                                                   const unsigned* __restrict__ boff,
                                                   int* __restrict__ idx) {
    const int t = threadIdx.x;
    const int lg = t & 15;
    const int grp = t >> 4;
    const int b = blockIdx.y;
    const int pq = blockIdx.x * 16 + grp;      // sorted position
    __shared__ u64 cbuf[16][64];
    __shared__ unsigned obuf[16][17];
    __shared__ int scnt[16];
    if (lg == 0) scnt[grp] = 0;
    __syncthreads();
    const int gq = sortidx[b * N + pq];
    const float4 q = cand4s[(size_t)b * N + pq];
    const float qq = q.w;
    const float T = Tbuf[b * N + pq];
    const float nq = sqrtf(qq);
    const float r = sqrtf(T) * 1.001f + 0.01f;
    const float lov = (nq > r) ? (nq - r) * (nq - r) : 0.f;
    const float hiv = (nq + r) * (nq + r);
    const int lob = nbucket(lov), hib = nbucket(hiv);
    const int start = (lob == 0) ? 0 : (int)boff[b * 256 + lob - 1];
    const int end = (int)boff[b * 256 + hib];
    const float4* cs = cand4s + (size_t)b * N;
    const int* si = sortidx + b * N;
    const int last = end - 1;
    for (int pos = start + lg; pos < end; pos += 64) {
        int p1 = pos + 16, p2 = pos + 32, p3 = pos + 48;
        float4 c0 = cs[pos];
        float4 c1 = cs[p1 < end ? p1 : last];
        float4 c2 = cs[p2 < end ? p2 : last];
        float4 c3 = cs[p3 < end ? p3 : last];
        float k0 = dist_key(q.x, q.y, q.z, qq, c0);
        float k1 = dist_key(q.x, q.y, q.z, qq, c1);
        float k2 = dist_key(q.x, q.y, q.z, qq, c2);
        float k3 = dist_key(q.x, q.y, q.z, qq, c3);
        if (k0 <= T) {
            int j = si[pos];
            if (j != gq) { int p = atomicAdd(&scnt[grp], 1); if (p < 64) cbuf[grp][p] = ((u64)__float_as_uint(k0) << 32) | (unsigned)j; }
        }
        if (k1 <= T && p1 < end) {
            int j = si[p1];
            if (j != gq) { int p = atomicAdd(&scnt[grp], 1); if (p < 64) cbuf[grp][p] = ((u64)__float_as_uint(k1) << 32) | (unsigned)j; }
        }
        if (k2 <= T && p2 < end) {
            int j = si[p2];
            if (j != gq) { int p = atomicAdd(&scnt[grp], 1); if (p < 64) cbuf[grp][p] = ((u64)__float_as_uint(k2) << 32) | (unsigned)j; }
        }
        if (k3 <= T && p3 < end) {
            int j = si[p3];
            if (j != gq) { int p = atomicAdd(&scnt[grp], 1); if (p < 64) cbuf[grp][p] = ((u64)__float_as_uint(k3) << 32) | (unsigned)j; }
        }
    }
    __syncthreads();
    int cnt = scnt[grp]; if (cnt > 64) cnt = 64;
    // rank selection over (keybits, idx) packs: exact top-16, lowest-index ties
    u64 mine[4]; bool have[4]; int rank[4];
#pragma unroll
    for (int e = 0; e < 4; ++e) {
        int pi = lg + e * 16;
        have[e] = pi < cnt;
        mine[e] = have[e] ? cbuf[grp][pi] : ~0ull;
        rank[e] = 0;
    }
    for (int m = 0; m < cnt; ++m) {
        u64 v = cbuf[grp][m];
#pragma unroll
        for (int e = 0; e < 4; ++e) rank[e] += (v < mine[e]) ? 1 : 0;
    }
    obuf[grp][1 + lg] = (unsigned)gq;   // defensive fill
    __syncthreads();
#pragma unroll
    for (int e = 0; e < 4; ++e)
        if (have[e] && rank[e] < 16)
            obuf[grp][1 + rank[e]] = (unsigned)(mine[e] & 0xFFFFFFFFu);
    if (lg == 0) obuf[grp][0] = (unsigned)gq;
    __syncthreads();
    int* op = idx + (size_t)(b * N + gq) * KTOT;
    op[lg] = (int)obuf[grp][lg];
    if (lg == 0) op[16] = (int)obuf[grp][16];
}

// ---------------- fused edge MLP via MFMA: direct-register B-fragments ----------------
// GEMM1's B-fragment for lane l IS lfb16[j*64 + ks*32 + hi*8 .. +8] -> load direct,
// no f_lds staging. xyz fragment (ks=2) computed in-register from cand4 (hi==0 lanes).
// h1 double-buffered in LDS -> ONE barrier per k-pair iteration (9 total).
__global__ __launch_bounds__(256) void ef_mlp_mfma(
        const unsigned short* __restrict__ lfb16, const float4* __restrict__ cand4,
        const int* __restrict__ idx,
        const unsigned short* __restrict__ W1p, const float* __restrict__ b_ef1,
        const unsigned short* __restrict__ W2p, const float* __restrict__ b_ef2,
        unsigned short* __restrict__ fmax_bf) {
    const int t = threadIdx.x;
    const int w = t >> 6;       // wave 0..3
    const int l = t & 63;
    const int hi = l >> 4;
    const int col = l & 15;     // point within block (B-fragment column)
    const int n0 = blockIdx.x * 16;
    const int b = blockIdx.y;

    __shared__ unsigned short h1_lds[2][32][264];  // double-buffered [slot*16+p][m]
    __shared__ int idx_l[16][17];

    for (int e = t; e < 16 * 17; e += 256) {
        int p = e / 17, k = e - p * 17;
        idx_l[p][k] = idx[(size_t)(b * N + n0 + p) * KTOT + k];
    }

    f32x4 b1i[4];   // GEMM1 bias as acc init
#pragma unroll
    for (int mt = 0; mt < 4; ++mt)
#pragma unroll
        for (int r = 0; r < 4; ++r)
            b1i[mt][r] = b_ef1[(w * 4 + mt) * 16 + (hi << 2) + r];
    f32x4 b2i[2];   // GEMM2 bias as acc init
#pragma unroll
    for (int i = 0; i < 2; ++i)
#pragma unroll
        for (int r = 0; r < 4; ++r)
            b2i[i][r] = b_ef2[(w * 2 + i) * 16 + (hi << 2) + r];

    bf16x8 A1[12];
#pragma unroll
    for (int mt = 0; mt < 4; ++mt)
#pragma unroll
        for (int ks = 0; ks < 3; ++ks)
            A1[mt * 3 + ks] = *(const bf16x8*)(W1p + (size_t)(((w * 4 + mt) * 3 + ks) * 64 + l) * 8);
    bf16x8 A2[16];
#pragma unroll
    for (int i = 0; i < 2; ++i)
#pragma unroll
        for (int ks = 0; ks < 8; ++ks)
            A2[i * 8 + ks] = *(const bf16x8*)(W2p + (size_t)(((w * 2 + i) * 8 + ks) * 64 + l) * 8);

    const unsigned short* lfb = lfb16 + (size_t)b * N * 64;
    const float4* cand4b = cand4 + (size_t)b * N;
    const float4 selfc = cand4b[n0 + col];

    __syncthreads();  // idx_l visible

    f32x4 rmax[2];
#pragma unroll
    for (int i = 0; i < 2; ++i)
#pragma unroll
        for (int r = 0; r < 4; ++r) rmax[i][r] = -1e30f;

    int buf = 0;
    for (int g = 0; g < KPAIR; ++g) {
        // ---- load B-fragments direct from global (L2-resident) ----
        bf16x8 B0[2], B1[2], B2[2];
        int jj[2];
#pragma unroll
        for (int nt = 0; nt < 2; ++nt) {
            int kk = 2 * g + nt; if (kk > 16) kk = 16;
            jj[nt] = idx_l[col][kk];
            const unsigned short* base = lfb + (size_t)jj[nt] * 64 + hi * 8;
            B0[nt] = *(const bf16x8*)base;          // channels ks=0
            B1[nt] = *(const bf16x8*)(base + 32);   // channels ks=1
        }
#pragma unroll
        for (int nt = 0; nt < 2; ++nt) {
            int kk = 2 * g + nt; if (kk > 16) kk = 16;
            union { unsigned u[4]; bf16x8 v; } z;
            z.u[0] = 0; z.u[1] = 0; z.u[2] = 0; z.u[3] = 0;
            if (hi == 0) {                           // channels 64..66 live here
                float4 nb = cand4b[jj[nt]];
                float dx = (kk == 0) ? selfc.x : selfc.x - nb.x;
                float dy = (kk == 0) ? selfc.y : selfc.y - nb.y;
                float dz = (kk == 0) ? selfc.z : selfc.z - nb.z;
                z.u[0] = cvt_pk_bf16(dx, dy);
                z.u[1] = cvt_pk_bf16(dz, 0.f);
            }
            B2[nt] = z.v;
        }
        // ---- GEMM1: 4mt x 2nt x 3ks = 24 MFMA ----
        f32x4 acc1[4][2];
#pragma unroll
        for (int mt = 0; mt < 4; ++mt)
#pragma unroll
            for (int nt = 0; nt < 2; ++nt) acc1[mt][nt] = b1i[mt];   // bias in C-init
#pragma unroll
        for (int nt = 0; nt < 2; ++nt)
#pragma unroll
            for (int mt = 0; mt < 4; ++mt) {
                acc1[mt][nt] = __builtin_amdgcn_mfma_f32_16x16x32_bf16(A1[mt * 3 + 0], B0[nt], acc1[mt][nt], 0, 0, 0);
                acc1[mt][nt] = __builtin_amdgcn_mfma_f32_16x16x32_bf16(A1[mt * 3 + 1], B1[nt], acc1[mt][nt], 0, 0, 0);
                acc1[mt][nt] = __builtin_amdgcn_mfma_f32_16x16x32_bf16(A1[mt * 3 + 2], B2[nt], acc1[mt][nt], 0, 0, 0);
            }
        // ---- h1 = lrelu(acc1) -> LDS[buf] ----
#pragma unroll
        for (int mt = 0; mt < 4; ++mt)
#pragma unroll
            for (int nt = 0; nt < 2; ++nt) {
                uint2 d;
                d.x = cvt_pk_bf16(lrelu(acc1[mt][nt][0]), lrelu(acc1[mt][nt][1]));
                d.y = cvt_pk_bf16(lrelu(acc1[mt][nt][2]), lrelu(acc1[mt][nt][3]));
                *(uint2*)&h1_lds[buf][nt * 16 + col][(w * 4 + mt) * 16 + (hi << 2)] = d;
            }
        __syncthreads();                 // h1(g) ready (single barrier/iter; dbuf)
        // ---- GEMM2: 2i x 2nt x 8ks = 32 MFMA ----
        f32x4 acc2[2][2];
#pragma unroll
        for (int i = 0; i < 2; ++i)
#pragma unroll
            for (int nt = 0; nt < 2; ++nt) acc2[i][nt] = b2i[i];     // bias in C-init
#pragma unroll
        for (int nt = 0; nt < 2; ++nt) {
            const int colr = nt * 16 + col;
#pragma unroll
            for (int ks = 0; ks < 8; ++ks) {
                bf16x8 Bf = *(const bf16x8*)&h1_lds[buf][colr][ks * 32 + hi * 8];
                acc2[0][nt] = __builtin_amdgcn_mfma_f32_16x16x32_bf16(A2[0 * 8 + ks], Bf, acc2[0][nt], 0, 0, 0);
                acc2[1][nt] = __builtin_amdgcn_mfma_f32_16x16x32_bf16(A2[1 * 8 + ks], Bf, acc2[1][nt], 0, 0, 0);
            }
        }
#pragma unroll
        for (int i = 0; i < 2; ++i)
#pragma unroll
            for (int nt = 0; nt < 2; ++nt)
#pragma unroll
                for (int r = 0; r < 4; ++r)
                    rmax[i][r] = fmaxf(rmax[i][r], acc2[i][nt][r]);
        buf ^= 1;
    }
    // bias already folded into acc2 -> rmax; store bf16
    const size_t nbase = ((size_t)(b * N + n0 + col)) * H2;
#pragma unroll
    for (int i = 0; i < 2; ++i) {
        uint2 d;
        d.x = cvt_pk_bf16(rmax[i][0], rmax[i][1]);
        d.y = cvt_pk_bf16(rmax[i][2], rmax[i][3]);
        *(uint2*)&fmax_bf[nbase + (w * 2 + i) * 16 + (hi << 2)] = d;
    }
}

// ---------------- fused final MLP via MFMA: 8 waves, halved per-wave tile ----------------
__global__ __launch_bounds__(512) void mlp_mfma(
        const unsigned short* __restrict__ lfb16, const float* __restrict__ pts,
        const unsigned short* __restrict__ fmax_bf, const float* __restrict__ gvec,
        const unsigned short* __restrict__ W1m, const unsigned short* __restrict__ W2m,
        const float* __restrict__ W3, const float* __restrict__ b2v,
        const float* __restrict__ b3v, float* __restrict__ out) {
    const int t = threadIdx.x;
    const int w2 = t >> 6;          // wave 0..7
    const int l = t & 63;
    const int ow = w2 >> 1;         // old wave coord in prepacked layout
    const int n0 = blockIdx.x * 32;
    const int b = blockIdx.y;

    __shared__ unsigned short feat_s[32 * 256];   // [n][256], swizzled
    __shared__ unsigned short y1c_s[32 * 256];    // [n][256], swizzled
    __shared__ float red[8][32];

    auto sw = [](int n, int cbyte) -> unsigned {
        return (unsigned)(n << 9) | ((unsigned)cbyte ^ (((unsigned)n & 7u) << 4));
    };
    char* featB = (char*)feat_s;
    char* y1cB = (char*)y1c_s;

    const unsigned short* lfb = lfb16 + (size_t)b * N * 64;
    for (int e = t; e < 32 * 64; e += 512) {       // local feats (bf16, raw copy)
        int c = e & 63, n = e >> 6;
        *(unsigned short*)(featB + sw(n, c * 2)) = lfb[(size_t)(n0 + n) * 64 + c];
    }
    for (int e = t; e < 32 * 128; e += 512) {      // fmax (bf16, raw copy)
        int c = e & 127, n = e >> 7;
        *(unsigned short*)(featB + sw(n, (64 + c) * 2)) =
            fmax_bf[((size_t)(b * N + n0 + n)) * H2 + c];
    }
    if (t < 96) {                                   // xyz
        int n = t & 31, d = t >> 5;
        *(unsigned short*)(featB + sw(n, (192 + d) * 2)) =
            f2bf(pts[((size_t)(b * 3 + d)) * N + n0 + n]);
    }
    for (int e = t; e < 32 * 29; e += 512) {       // zero pad k=195..223
        int n = e / 29, c = 195 + e % 29;
        *(unsigned short*)(featB + sw(n, c * 2)) = 0;
    }
    __syncthreads();

    f32x4 accB[2][2];
#pragma unroll
    for (int mt = 0; mt < 2; ++mt)
#pragma unroll
        for (int nt = 0; nt < 2; ++nt)
            accB[mt][nt] = (f32x4){0.f, 0.f, 0.f, 0.f};

    for (int ch = 0; ch < 4; ++ch) {
        bf16x8 A1[2][7];
#pragma unroll
        for (int mt = 0; mt < 2; ++mt) {
            const int omt = (w2 & 1) * 2 + mt;
#pragma unroll
            for (int ks = 0; ks < 7; ++ks)
                A1[mt][ks] = *(const bf16x8*)(W1m +
                    (size_t)((((ch * 4 + ow) * 4 + omt) * 7 + ks) * 64 + l) * 8);
        }
        f32x4 accA[2][2];
#pragma unroll
        for (int mt = 0; mt < 2; ++mt) {
            const int m = w2 * 32 + mt * 16 + ((l >> 4) << 2);
            const f32x4 gv = *(const f32x4*)(gvec + b * O1 + ch * 256 + m);
#pragma unroll
            for (int nt = 0; nt < 2; ++nt)
                accA[mt][nt] = gv;                       // gvec bias in C-init
        }
#pragma unroll
        for (int nt = 0; nt < 2; ++nt) {
            const int n = nt * 16 + (l & 15);
#pragma unroll
            for (int ks = 0; ks < 7; ++ks) {
                bf16x8 Bf = *(const bf16x8*)(featB + sw(n, ks * 64 + (l >> 4) * 16));
#pragma unroll
                for (int mt = 0; mt < 2; ++mt)
                    accA[mt][nt] = __builtin_amdgcn_mfma_f32_16x16x32_bf16(
                        A1[mt][ks], Bf, accA[mt][nt], 0, 0, 0);
            }
        }
        bf16x8 A2[2][8];
#pragma unroll
        for (int mt = 0; mt < 2; ++mt) {
            const int omt = (w2 & 1) * 2 + mt;
#pragma unroll
            for (int ks = 0; ks < 8; ++ks)
                A2[mt][ks] = *(const bf16x8*)(W2m +
                    (size_t)((((ch * 4 + ow) * 4 + omt) * 8 + ks) * 64 + l) * 8);
        }
        if (ch) __syncthreads();
#pragma unroll
        for (int mt = 0; mt < 2; ++mt) {
            const int m = w2 * 32 + mt * 16 + ((l >> 4) << 2);
#pragma unroll
            for (int nt = 0; nt < 2; ++nt) {
                const int n = nt * 16 + (l & 15);
                uint2 d;
                d.x = cvt_pk_bf16(lrelu(accA[mt][nt][0]), lrelu(accA[mt][nt][1]));
                d.y = cvt_pk_bf16(lrelu(accA[mt][nt][2]), lrelu(accA[mt][nt][3]));
                *(uint2*)(y1cB + sw(n, m * 2)) = d;
            }
        }
        __syncthreads();
#pragma unroll
        for (int nt = 0; nt < 2; ++nt) {
            const int n = nt * 16 + (l & 15);
#pragma unroll
            for (int ks = 0; ks < 8; ++ks) {
                bf16x8 Bf = *(const bf16x8*)(y1cB + sw(n, ks * 64 + (l >> 4) * 16));
#pragma unroll
                for (int mt = 0; mt < 2; ++mt)
                    accB[mt][nt] = __builtin_amdgcn_mfma_f32_16x16x32_bf16(
                        A2[mt][ks], Bf, accB[mt][nt], 0, 0, 0);
            }
        }
    }

    float p0 = 0.f, p1 = 0.f;
#pragma unroll
    for (int mt = 0; mt < 2; ++mt) {
        const int m = w2 * 32 + mt * 16 + ((l >> 4) << 2);
        const f32x4 bb = *(const f32x4*)(b2v + m);
        const f32x4 w3 = *(const f32x4*)(W3 + m);
#pragma unroll
        for (int r = 0; r < 4; ++r) {
            p0 = fmaf(w3[r], lrelu(accB[mt][0][r] + bb[r]), p0);
            p1 = fmaf(w3[r], lrelu(accB[mt][1][r] + bb[r]), p1);
        }
    }
    p0 += __shfl_xor(p0, 16); p0 += __shfl_xor(p0, 32);
    p1 += __shfl_xor(p1, 16); p1 += __shfl_xor(p1, 32);
    if (l < 16) { red[w2][l] = p0; red[w2][16 + l] = p1; }
    __syncthreads();
    if (t < 32) {
        float s = b3v[0];
#pragma unroll
        for (int ww = 0; ww < 8; ++ww) s += red[ww][t];
        out[(size_t)b * N + n0 + t] = s;
    }
}

extern "C" void kernel_launch(void* const* d_in, const int* in_sizes, int n_in,
                              void* d_out, int out_size, void* d_ws, size_t ws_size,
                              hipStream_t stream) {
    const float* g     = (const float*)d_in[0];
    const float* pts   = (const float*)d_in[1];
    const float* lf    = (const float*)d_in[2];
    const float* W_ef1 = (const float*)d_in[3];
    const float* b_ef1 = (const float*)d_in[4];
    const float* W_ef2 = (const float*)d_in[5];
    const float* b_ef2 = (const float*)d_in[6];
    const float* W1    = (const float*)d_in[7];
    const float* b1    = (const float*)d_in[8];
    const float* W2    = (const float*)d_in[9];
    const float* b2    = (const float*)d_in[10];
    const float* W3    = (const float*)d_in[11];
    const float* b3    = (const float*)d_in[12];
    float* out = (float*)d_out;

    char* ws = (char*)d_ws;
    int*      idx     = (int*)ws;     ws += (size_t)B * N * KTOT * 4;
    float4*   cand4   = (float4*)ws;  ws += (size_t)B * N * 16;
    float4*   cand4s  = (float4*)ws;  ws += (size_t)B * N * 16;
    int*      sortidx = (int*)ws;     ws += (size_t)B * N * 4;
    unsigned* hist    = (unsigned*)ws; ws += (size_t)B * 256 * 4;
    unsigned* boff    = (unsigned*)ws; ws += (size_t)B * 256 * 4;
    float*    topd    = (float*)ws;
    unsigned short* fmax_bf = (unsigned short*)topd;  // alias: topd dead before ef writes fmax
    ws += (size_t)B * NCHW * 16 * N * 4;
    float*    Tbuf  = (float*)ws;    ws += (size_t)B * N * 4;
    float*    gvec  = (float*)ws;    ws += (size_t)B * O1 * 4;
    unsigned short* lfb16 = (unsigned short*)ws; ws += (size_t)B * N * 64 * 2;
    unsigned short* W1p = (unsigned short*)ws; ws += (size_t)S1 * 2;
    unsigned short* W2p = (unsigned short*)ws; ws += (size_t)S2 * 2;
    unsigned short* W1m = (unsigned short*)ws; ws += (size_t)S3 * 2;
    unsigned short* W2m = (unsigned short*)ws; ws += (size_t)S4 * 2;

    hipMemsetAsync(hist, 0, (size_t)B * 256 * 4, stream);
    prep_cand4_hist<<<dim3((B * N) / 256), 256, 0, stream>>>(pts, cand4, hist);
    prep_lf_bf<<<dim3((B * N * 64) / 256), 256, 0, stream>>>(lf, lfb16);
    prepack_all<<<dim3((S1 + S2 + S3 + S4) / 256), 256, 0, stream>>>(
        W_ef1, W_ef2, W1, W2, W1p, W2p, W1m, W2m);
    gvec_kernel<<<dim3(O1 / 4, B), 256, 0, stream>>>(W1, b1, g, gvec);
    knn_prefix<<<dim3(1), 256, 0, stream>>>(hist, boff);
    knn_scatter<<<dim3((B * N) / 256), 256, 0, stream>>>(cand4, boff, cand4s, sortidx);
    knn_pass1w<<<dim3(N / 256, NCHW, B), 256, 0, stream>>>(cand4s, topd);
    knn_thresh<<<dim3(N / 256, B), 256, 0, stream>>>(topd, Tbuf);
    knn_recover<<<dim3(N / 16, B), 256, 0, stream>>>(cand4s, sortidx, Tbuf, boff, idx);
    ef_mlp_mfma<<<dim3(N / 16, B), 256, 0, stream>>>(lfb16, cand4, idx, W1p, b_ef1, W2p, b_ef2, fmax_bf);
    mlp_mfma<<<dim3(N / 32, B), 512, 0, stream>>>(lfb16, pts, fmax_bf, gvec, W1m, W2m, W3, b2, b3, out);
}

// Round 20
// 200.621 us; speedup vs baseline: 1.0651x; 1.0651x over previous
//
#include <hip/hip_runtime.h>
#include <hip/hip_bf16.h>
#include <cstdint>

#define B 2
#define N 8192
#define KTOT 17        // self + 16 neighbors
#define CL 64
#define CEF 67         // CL + 3
#define H1 256
#define H2 128
#define CG 1024
#define O1 1024
#define O2 256
#define NCHW 8               // window chunks
#define WCH 256              // window chunk size (window = 2048)
#define KPAIR 9              // ef: 9 pairs of k-slots (17 -> 18, last duplicated)

typedef unsigned long long u64;
typedef __bf16 bf16x8 __attribute__((ext_vector_type(8)));
typedef float f32x4 __attribute__((ext_vector_type(4)));

__device__ __forceinline__ float lrelu(float v) { return fmaxf(v, 0.01f * v); }

__device__ __forceinline__ unsigned short f2bf(float f) {  // RNE
    union { float f; unsigned u; } v; v.f = f;
    unsigned r = v.u + 0x7FFFu + ((v.u >> 16) & 1u);
    return (unsigned short)(r >> 16);
}

// HW packed f32->bf16 (gfx950): low half = lo, high half = hi
__device__ __forceinline__ unsigned cvt_pk_bf16(float lo, float hi) {
    unsigned r;
    asm("v_cvt_pk_bf16_f32 %0, %1, %2" : "=v"(r) : "v"(lo), "v"(hi));
    return r;
}

__device__ __forceinline__ float norm3(float x, float y, float z) {
    return __fmaf_rn(z, z, __fmaf_rn(y, y, __fmul_rn(x, x)));
}
// d^2-scale key; MUST be byte-identical between pass1w and recover.
__device__ __forceinline__ float dist_key(float qx, float qy, float qz, float qq,
                                          float4 c) {
    float dot = __fmaf_rn(qz, c.z, __fmaf_rn(qy, c.y, __fmul_rn(qx, c.x)));
    float t = __fmaf_rn(-2.f, dot, qq);
    return fmaxf(__fadd_rn(t, c.w), 0.f);
}

__device__ __forceinline__ int nbucket(float nn) {
    return (int)fminf(nn * 16.f, 255.f);
}

// ---------------- fused: pack candidates + norm histogram ----------------
__global__ void prep_cand4_hist(const float* __restrict__ pts, float4* __restrict__ cand4,
                                unsigned* __restrict__ hist) {
    int id = blockIdx.x * 256 + threadIdx.x;       // B*N threads
    int b = id >> 13, j = id & (N - 1);
    const float* px = pts + (size_t)b * 3 * N;
    float x = px[j], y = px[N + j], z = px[2 * N + j];
    float nn = norm3(x, y, z);
    cand4[id] = make_float4(x, y, z, nn);
    atomicAdd(&hist[b * 256 + nbucket(nn)], 1u);
}

__global__ void knn_prefix(const unsigned* __restrict__ hist, unsigned* __restrict__ boff) {
    __shared__ unsigned s[256];
    int t = threadIdx.x;
    for (int b = 0; b < B; ++b) {
        s[t] = hist[b * 256 + t];
        __syncthreads();
        for (int d = 1; d < 256; d <<= 1) {
            unsigned v = (t >= d) ? s[t - d] : 0u;
            __syncthreads();
            s[t] += v;
            __syncthreads();
        }
        boff[b * 256 + t] = s[t] - hist[b * 256 + t];  // exclusive prefix
        __syncthreads();
    }
}
__global__ void knn_scatter(const float4* __restrict__ cand4, unsigned* __restrict__ boff,
                            float4* __restrict__ cand4s, int* __restrict__ sortidx) {
    int id = blockIdx.x * 256 + threadIdx.x;
    int b = id >> 13, j = id & (N - 1);
    float4 c = cand4[id];
    unsigned pos = atomicAdd(&boff[b * 256 + nbucket(c.w)], 1u);
    cand4s[(size_t)b * N + pos] = c;
    sortidx[b * N + pos] = j;
}
// NOTE: after knn_scatter, boff[b*256+k] == INCLUSIVE prefix (end of bucket k).

// ---------------- fused prepack: all 4 weight tensors in one dispatch ----------------
#define S1 24576            // ef W1 frags
#define S2 32768            // ef W2 frags
#define S3 229376           // mlp W1 frags
#define S4 262144           // mlp W2 frags
__global__ void prepack_all(const float* __restrict__ W_ef1, const float* __restrict__ W_ef2,
                            const float* __restrict__ W1, const float* __restrict__ W2,
                            unsigned short* __restrict__ W1p, unsigned short* __restrict__ W2p,
                            unsigned short* __restrict__ W1m, unsigned short* __restrict__ W2m) {
    int id = blockIdx.x * 256 + threadIdx.x;
    if (id < S1) {
        int j = id & 7, l = (id >> 3) & 63, rest = id >> 9;
        int ks = rest % 3, mt = rest / 3;
        int m = mt * 16 + (l & 15);
        int k = ks * 32 + ((l >> 4) << 3) + j;
        W1p[id] = f2bf((k < CEF) ? W_ef1[m * CEF + k] : 0.f);
        return;
    }
    id -= S1;
    if (id < S2) {
        int j = id & 7, l = (id >> 3) & 63, rest = id >> 9;
        int ks = rest & 7, mt = rest >> 3;
        int m = mt * 16 + (l & 15);
        int k = ks * 32 + ((l >> 4) << 3) + j;
        W2p[id] = f2bf(W_ef2[m * H1 + k]);
        return;
    }
    id -= S2;
    if (id < S3) {
        int j = id & 7, l = (id >> 3) & 63, rest = id >> 9;
        int ks = rest % 7; int rest2 = rest / 7;
        int mt = rest2 & 3, w = (rest2 >> 2) & 3, ch = rest2 >> 4;
        int m = ch * 256 + w * 64 + mt * 16 + (l & 15);
        int k = ks * 32 + ((l >> 4) << 3) + j;
        W1m[id] = (k < 195) ? f2bf(W1[(size_t)m * 1219 + 1024 + k]) : (unsigned short)0;
        return;
    }
    id -= S3;
    if (id < S4) {
        int j = id & 7, l = (id >> 3) & 63, rest = id >> 9;
        int ks = rest & 7; int rest2 = rest >> 3;
        int mt = rest2 & 3, w = (rest2 >> 2) & 3, ch = rest2 >> 4;
        int m = w * 64 + mt * 16 + (l & 15);
        int k = ch * 256 + ks * 32 + ((l >> 4) << 3) + j;
        W2m[id] = f2bf(W2[(size_t)m * 1024 + k]);
    }
}

// ---------------- prep lf to point-major bf16 ----------------
__global__ void prep_lf_bf(const float* __restrict__ lf, unsigned short* __restrict__ out) {
    int id = blockIdx.x * 256 + threadIdx.x;       // B*N*64 threads
    int c = id & 63;
    int n = (id >> 6) & (N - 1);
    int b = id >> 19;
    out[id] = f2bf(lf[((size_t)b * CL + c) * N + n]);
}

// ---------------- gvec: one wave per output row, shuffle reduce ----------------
__global__ __launch_bounds__(256) void gvec_kernel(const float* __restrict__ W1,
                                                   const float* __restrict__ b1,
                                                   const float* __restrict__ g,
                                                   float* __restrict__ gvec) {
    const int t = threadIdx.x;
    const int l = t & 63;
    const int o = blockIdx.x * 4 + (t >> 6);   // 0..1023
    const int b = blockIdx.y;
    const float* row = W1 + (size_t)o * 1219;
    const float* gb = g + b * CG;
    float s = 0.f;
#pragma unroll
    for (int i = 0; i < CG / 64; ++i)
        s = fmaf(row[l + i * 64], gb[l + i * 64], s);
    s += __shfl_xor(s, 1);  s += __shfl_xor(s, 2);  s += __shfl_xor(s, 4);
    s += __shfl_xor(s, 8);  s += __shfl_xor(s, 16); s += __shfl_xor(s, 32);
    if (l == 0) gvec[b * O1 + o] = s + b1[o];
}

// ---------------- KNN pass1w: top-16 over 2048 norm-window (8 chunks x 256) ----------------
__global__ __launch_bounds__(256) void knn_pass1w(const float4* __restrict__ cand4s,
                                                  float* __restrict__ topd) {
    const int t = threadIdx.x;
    const int x = blockIdx.x;       // query block (sorted positions x*256..+256)
    const int chunk = blockIdx.y;   // 0..7
    const int b = blockIdx.z;
    int wstart = x * 256 - 896;
    wstart = wstart < 0 ? 0 : (wstart > N - 2048 ? N - 2048 : wstart);
    const int p = x * 256 + t;                  // sorted position of query
    const int rel = p - wstart - chunk * WCH;   // self slot in this chunk (may be OOR)
    const float4 q = cand4s[(size_t)b * N + p];
    const float qq = q.w;
    const float4* cb = cand4s + (size_t)b * N + wstart + chunk * WCH;
    float qd[16];
#pragma unroll
    for (int r = 0; r < 16; ++r) qd[r] = __builtin_inff();
#pragma unroll 8
    for (int s = 0; s < WCH; ++s) {
        float key = dist_key(q.x, q.y, q.z, qq, cb[s]);
        if (s == rel) key = __builtin_inff();   // exclude self
#pragma unroll
        for (int r = 15; r >= 1; --r)
            qd[r] = __builtin_amdgcn_fmed3f(key, qd[r - 1], qd[r]);
        qd[0] = fminf(key, qd[0]);
    }
#pragma unroll
    for (int s = 0; s < 16; ++s)
        topd[(size_t)((b * NCHW + chunk) * 16 + s) * N + p] = qd[s];
}

// ---------------- KNN thresh: merge 8 window lists -> T' (position-indexed) ----------------
__global__ __launch_bounds__(256) void knn_thresh(const float* __restrict__ topd,
                                                  float* __restrict__ Tbuf) {
    const int t = threadIdx.x;
    const int i = blockIdx.x * 256 + t;   // sorted position
    const int b = blockIdx.y;
    float qd[16];
#pragma unroll
    for (int s = 0; s < 16; ++s)
        qd[s] = topd[(size_t)((b * NCHW + 0) * 16 + s) * N + i];
    for (int c = 1; c < NCHW; ++c) {
        for (int s = 0; s < 16; ++s) {
            float pk = topd[(size_t)((b * NCHW + c) * 16 + s) * N + i];
            if (pk >= qd[15]) break;  // sorted: rest of chunk also fails
#pragma unroll
            for (int r = 15; r >= 1; --r)
                qd[r] = __builtin_amdgcn_fmed3f(pk, qd[r - 1], qd[r]);
            qd[0] = fminf(pk, qd[0]);
        }
    }
    Tbuf[b * N + i] = qd[15];
}

// ---------------- KNN recover: norm-windowed scan (4x unrolled), exact rank-select 16 ----------------
__global__ __launch_bounds__(256) void knn_recover(const float4* __restrict__ cand4s,
                                                   const int* __restrict__ sortidx,
                                                   const float* __restrict__ Tbuf,
                                                   const unsigned* __restrict__ boff,
                                                   int* __restrict__ idx) {
    const int t = threadIdx.x;
    const int lg = t & 15;
    const int grp = t >> 4;
    const int b = blockIdx.y;
    const int pq = blockIdx.x * 16 + grp;      // sorted position
    __shared__ u64 cbuf[16][64];
    __shared__ unsigned obuf[16][17];
    __shared__ int scnt[16];
    if (lg == 0) scnt[grp] = 0;
    __syncthreads();
    const int gq = sortidx[b * N + pq];
    const float4 q = cand4s[(size_t)b * N + pq];
    const float qq = q.w;
    const float T = Tbuf[b * N + pq];
    const float nq = sqrtf(qq);
    const float r = sqrtf(T) * 1.001f + 0.01f;
    const float lov = (nq > r) ? (nq - r) * (nq - r) : 0.f;
    const float hiv = (nq + r) * (nq + r);
    const int lob = nbucket(lov), hib = nbucket(hiv);
    const int start = (lob == 0) ? 0 : (int)boff[b * 256 + lob - 1];
    const int end = (int)boff[b * 256 + hib];
    const float4* cs = cand4s + (size_t)b * N;
    const int* si = sortidx + b * N;
    const int last = end - 1;
    for (int pos = start + lg; pos < end; pos += 64) {
        int p1 = pos + 16, p2 = pos + 32, p3 = pos + 48;
        float4 c0 = cs[pos];
        float4 c1 = cs[p1 < end ? p1 : last];
        float4 c2 = cs[p2 < end ? p2 : last];
        float4 c3 = cs[p3 < end ? p3 : last];
        float k0 = dist_key(q.x, q.y, q.z, qq, c0);
        float k1 = dist_key(q.x, q.y, q.z, qq, c1);
        float k2 = dist_key(q.x, q.y, q.z, qq, c2);
        float k3 = dist_key(q.x, q.y, q.z, qq, c3);
        if (k0 <= T) {
            int j = si[pos];
            if (j != gq) { int p = atomicAdd(&scnt[grp], 1); if (p < 64) cbuf[grp][p] = ((u64)__float_as_uint(k0) << 32) | (unsigned)j; }
        }
        if (k1 <= T && p1 < end) {
            int j = si[p1];
            if (j != gq) { int p = atomicAdd(&scnt[grp], 1); if (p < 64) cbuf[grp][p] = ((u64)__float_as_uint(k1) << 32) | (unsigned)j; }
        }
        if (k2 <= T && p2 < end) {
            int j = si[p2];
            if (j != gq) { int p = atomicAdd(&scnt[grp], 1); if (p < 64) cbuf[grp][p] = ((u64)__float_as_uint(k2) << 32) | (unsigned)j; }
        }
        if (k3 <= T && p3 < end) {
            int j = si[p3];
            if (j != gq) { int p = atomicAdd(&scnt[grp], 1); if (p < 64) cbuf[grp][p] = ((u64)__float_as_uint(k3) << 32) | (unsigned)j; }
        }
    }
    __syncthreads();
    int cnt = scnt[grp]; if (cnt > 64) cnt = 64;
    // rank selection over (keybits, idx) packs: exact top-16, lowest-index ties
    u64 mine[4]; bool have[4]; int rank[4];
#pragma unroll
    for (int e = 0; e < 4; ++e) {
        int pi = lg + e * 16;
        have[e] = pi < cnt;
        mine[e] = have[e] ? cbuf[grp][pi] : ~0ull;
        rank[e] = 0;
    }
    for (int m = 0; m < cnt; ++m) {
        u64 v = cbuf[grp][m];
#pragma unroll
        for (int e = 0; e < 4; ++e) rank[e] += (v < mine[e]) ? 1 : 0;
    }
    obuf[grp][1 + lg] = (unsigned)gq;   // defensive fill
    __syncthreads();
#pragma unroll
    for (int e = 0; e < 4; ++e)
        if (have[e] && rank[e] < 16)
            obuf[grp][1 + rank[e]] = (unsigned)(mine[e] & 0xFFFFFFFFu);
    if (lg == 0) obuf[grp][0] = (unsigned)gq;
    __syncthreads();
    int* op = idx + (size_t)(b * N + gq) * KTOT;
    op[lg] = (int)obuf[grp][lg];
    if (lg == 0) op[16] = (int)obuf[grp][16];
}

// ---------------- fused edge MLP via MFMA: 2 k-slots/iter, point-major bf16 gather ----------------
// (R17-proven version: f_lds staging + register prefetch, 2 barriers/iter)
__global__ __launch_bounds__(256) void ef_mlp_mfma(
        const unsigned short* __restrict__ lfb16, const float4* __restrict__ cand4,
        const int* __restrict__ idx,
        const unsigned short* __restrict__ W1p, const float* __restrict__ b_ef1,
        const unsigned short* __restrict__ W2p, const float* __restrict__ b_ef2,
        unsigned short* __restrict__ fmax_bf) {
    const int t = threadIdx.x;
    const int w = t >> 6;       // wave 0..3
    const int l = t & 63;
    const int n0 = blockIdx.x * 16;
    const int b = blockIdx.y;

    __shared__ unsigned short f_lds[32][104];   // [slot*16+p][c 0..95]
    __shared__ unsigned short h1_lds[32][264];  // [slot*16+p][m]
    __shared__ int idx_l[16][17];

    for (int e = t; e < 16 * 17; e += 256) {
        int p = e / 17, k = e - p * 17;
        idx_l[p][k] = idx[(size_t)(b * N + n0 + p) * KTOT + k];
    }
    for (int e = t; e < 32 * 29; e += 256) {    // zero rows 67..95 once
        int col = e / 29, rr = 67 + e % 29;
        f_lds[col][rr] = 0;
    }

    f32x4 b1i[4];   // GEMM1 bias as acc init
#pragma unroll
    for (int mt = 0; mt < 4; ++mt)
#pragma unroll
        for (int r = 0; r < 4; ++r)
            b1i[mt][r] = b_ef1[(w * 4 + mt) * 16 + ((l >> 4) << 2) + r];
    f32x4 b2i[2];   // GEMM2 bias as acc init
#pragma unroll
    for (int i = 0; i < 2; ++i)
#pragma unroll
        for (int r = 0; r < 4; ++r)
            b2i[i][r] = b_ef2[(w * 2 + i) * 16 + ((l >> 4) << 2) + r];

    bf16x8 A1[12];
#pragma unroll
    for (int mt = 0; mt < 4; ++mt)
#pragma unroll
        for (int ks = 0; ks < 3; ++ks)
            A1[mt * 3 + ks] = *(const bf16x8*)(W1p + (size_t)(((w * 4 + mt) * 3 + ks) * 64 + l) * 8);
    bf16x8 A2[16];
#pragma unroll
    for (int i = 0; i < 2; ++i)
#pragma unroll
        for (int ks = 0; ks < 8; ++ks)
            A2[i * 8 + ks] = *(const bf16x8*)(W2p + (size_t)(((w * 2 + i) * 8 + ks) * 64 + l) * 8);

    const int p_my = t >> 4;
    const int cbr = (t & 15) * 4;               // channel base (4 channels/thread)
    const unsigned short* lfb = lfb16 + (size_t)b * N * 64;
    const float4* cand4b = cand4 + (size_t)b * N;
    float selfp = 0.f;
    if (t < 48) selfp = ((const float*)(cand4b + n0 + (t & 15)))[t >> 4];

    __syncthreads();  // idx_l + zero rows visible

    uint2 rbf[2];     // 2 slots x 4 bf16 channels (pre-converted)
    float rp[2];      // xyz gather (t<48)
    auto prefetch = [&](int g) {
#pragma unroll
        for (int sl = 0; sl < 2; ++sl) {
            int kk = 2 * g + sl; if (kk > 16) kk = 16;
            int j = idx_l[p_my][kk];
            rbf[sl] = *(const uint2*)(lfb + (size_t)j * 64 + cbr);
        }
        if (t < 48) {
#pragma unroll
            for (int sl = 0; sl < 2; ++sl) {
                int kk = 2 * g + sl; if (kk > 16) kk = 16;
                int j = idx_l[t & 15][kk];
                rp[sl] = ((const float*)(cand4b + j))[t >> 4];
            }
        }
    };
    auto commit = [&](int g) {
#pragma unroll
        for (int sl = 0; sl < 2; ++sl)
            *(uint2*)&f_lds[sl * 16 + p_my][cbr] = rbf[sl];   // raw copy, no cvt
        if (t < 48) {
#pragma unroll
            for (int sl = 0; sl < 2; ++sl) {
                int kk = 2 * g + sl; if (kk > 16) kk = 16;
                float v = (kk == 0) ? selfp : selfp - rp[sl];
                f_lds[sl * 16 + (t & 15)][64 + (t >> 4)] = f2bf(v);
            }
        }
    };

    prefetch(0);
    f32x4 rmax[2];
#pragma unroll
    for (int i = 0; i < 2; ++i)
#pragma unroll
        for (int r = 0; r < 4; ++r) rmax[i][r] = -1e30f;

    for (int g = 0; g < KPAIR; ++g) {
        commit(g);
        __syncthreads();                 // A: f(g) ready; prev GEMM2 h1-reads done
        if (g < KPAIR - 1) prefetch(g + 1);
        f32x4 acc1[4][2];
#pragma unroll
        for (int mt = 0; mt < 4; ++mt)
#pragma unroll
            for (int nt = 0; nt < 2; ++nt) acc1[mt][nt] = b1i[mt];   // bias in C-init
#pragma unroll
        for (int nt = 0; nt < 2; ++nt) {
            const int col = nt * 16 + (l & 15);
            bf16x8 Bf0 = *(const bf16x8*)&f_lds[col][(l >> 4) * 8];
            bf16x8 Bf1 = *(const bf16x8*)&f_lds[col][32 + (l >> 4) * 8];
            bf16x8 Bf2 = *(const bf16x8*)&f_lds[col][64 + (l >> 4) * 8];
#pragma unroll
            for (int mt = 0; mt < 4; ++mt) {
                acc1[mt][nt] = __builtin_amdgcn_mfma_f32_16x16x32_bf16(A1[mt * 3 + 0], Bf0, acc1[mt][nt], 0, 0, 0);
                acc1[mt][nt] = __builtin_amdgcn_mfma_f32_16x16x32_bf16(A1[mt * 3 + 1], Bf1, acc1[mt][nt], 0, 0, 0);
                acc1[mt][nt] = __builtin_amdgcn_mfma_f32_16x16x32_bf16(A1[mt * 3 + 2], Bf2, acc1[mt][nt], 0, 0, 0);
            }
        }
#pragma unroll
        for (int mt = 0; mt < 4; ++mt)
#pragma unroll
            for (int nt = 0; nt < 2; ++nt) {
                uint2 d;
                d.x = cvt_pk_bf16(lrelu(acc1[mt][nt][0]), lrelu(acc1[mt][nt][1]));
                d.y = cvt_pk_bf16(lrelu(acc1[mt][nt][2]), lrelu(acc1[mt][nt][3]));
                *(uint2*)&h1_lds[nt * 16 + (l & 15)][(w * 4 + mt) * 16 + ((l >> 4) << 2)] = d;
            }
        __syncthreads();                 // B: h1(g) ready; all f(g)-reads done
        f32x4 acc2[2][2];
#pragma unroll
        for (int i = 0; i < 2; ++i)
#pragma unroll
            for (int nt = 0; nt < 2; ++nt) acc2[i][nt] = b2i[i];     // bias in C-init
#pragma unroll
        for (int nt = 0; nt < 2; ++nt) {
            const int col = nt * 16 + (l & 15);
#pragma unroll
            for (int ks = 0; ks < 8; ++ks) {
                bf16x8 Bf = *(const bf16x8*)&h1_lds[col][ks * 32 + (l >> 4) * 8];
                acc2[0][nt] = __builtin_amdgcn_mfma_f32_16x16x32_bf16(A2[0 * 8 + ks], Bf, acc2[0][nt], 0, 0, 0);
                acc2[1][nt] = __builtin_amdgcn_mfma_f32_16x16x32_bf16(A2[1 * 8 + ks], Bf, acc2[1][nt], 0, 0, 0);
            }
        }
#pragma unroll
        for (int i = 0; i < 2; ++i)
#pragma unroll
            for (int nt = 0; nt < 2; ++nt)
#pragma unroll
                for (int r = 0; r < 4; ++r)
                    rmax[i][r] = fmaxf(rmax[i][r], acc2[i][nt][r]);
    }
    // bias already folded into acc2 -> rmax; store bf16
    const size_t nbase = ((size_t)(b * N + n0 + (l & 15))) * H2;
#pragma unroll
    for (int i = 0; i < 2; ++i) {
        uint2 d;
        d.x = cvt_pk_bf16(rmax[i][0], rmax[i][1]);
        d.y = cvt_pk_bf16(rmax[i][2], rmax[i][3]);
        *(uint2*)&fmax_bf[nbase + (w * 2 + i) * 16 + ((l >> 4) << 2)] = d;
    }
}

// ---------------- fused final MLP via MFMA: 8 waves, halved per-wave tile ----------------
__global__ __launch_bounds__(512) void mlp_mfma(
        const unsigned short* __restrict__ lfb16, const float* __restrict__ pts,
        const unsigned short* __restrict__ fmax_bf, const float* __restrict__ gvec,
        const unsigned short* __restrict__ W1m, const unsigned short* __restrict__ W2m,
        const float* __restrict__ W3, const float* __restrict__ b2v,
        const float* __restrict__ b3v, float* __restrict__ out) {
    const int t = threadIdx.x;
    const int w2 = t >> 6;          // wave 0..7
    const int l = t & 63;
    const int ow = w2 >> 1;         // old wave coord in prepacked layout
    const int n0 = blockIdx.x * 32;
    const int b = blockIdx.y;

    __shared__ unsigned short feat_s[32 * 256];   // [n][256], swizzled
    __shared__ unsigned short y1c_s[32 * 256];    // [n][256], swizzled
    __shared__ float red[8][32];

    auto sw = [](int n, int cbyte) -> unsigned {
        return (unsigned)(n << 9) | ((unsigned)cbyte ^ (((unsigned)n & 7u) << 4));
    };
    char* featB = (char*)feat_s;
    char* y1cB = (char*)y1c_s;

    const unsigned short* lfb = lfb16 + (size_t)b * N * 64;
    for (int e = t; e < 32 * 64; e += 512) {       // local feats (bf16, raw copy)
        int c = e & 63, n = e >> 6;
        *(unsigned short*)(featB + sw(n, c * 2)) = lfb[(size_t)(n0 + n) * 64 + c];
    }
    for (int e = t; e < 32 * 128; e += 512) {      // fmax (bf16, raw copy)
        int c = e & 127, n = e >> 7;
        *(unsigned short*)(featB + sw(n, (64 + c) * 2)) =
            fmax_bf[((size_t)(b * N + n0 + n)) * H2 + c];
    }
    if (t < 96) {                                   // xyz
        int n = t & 31, d = t >> 5;
        *(unsigned short*)(featB + sw(n, (192 + d) * 2)) =
            f2bf(pts[((size_t)(b * 3 + d)) * N + n0 + n]);
    }
    for (int e = t; e < 32 * 29; e += 512) {       // zero pad k=195..223
        int n = e / 29, c = 195 + e % 29;
        *(unsigned short*)(featB + sw(n, c * 2)) = 0;
    }
    __syncthreads();

    f32x4 accB[2][2];
#pragma unroll
    for (int mt = 0; mt < 2; ++mt)
#pragma unroll
        for (int nt = 0; nt < 2; ++nt)
            accB[mt][nt] = (f32x4){0.f, 0.f, 0.f, 0.f};

    for (int ch = 0; ch < 4; ++ch) {
        bf16x8 A1[2][7];
#pragma unroll
        for (int mt = 0; mt < 2; ++mt) {
            const int omt = (w2 & 1) * 2 + mt;
#pragma unroll
            for (int ks = 0; ks < 7; ++ks)
                A1[mt][ks] = *(const bf16x8*)(W1m +
                    (size_t)((((ch * 4 + ow) * 4 + omt) * 7 + ks) * 64 + l) * 8);
        }
        f32x4 accA[2][2];
#pragma unroll
        for (int mt = 0; mt < 2; ++mt) {
            const int m = w2 * 32 + mt * 16 + ((l >> 4) << 2);
            const f32x4 gv = *(const f32x4*)(gvec + b * O1 + ch * 256 + m);
#pragma unroll
            for (int nt = 0; nt < 2; ++nt)
                accA[mt][nt] = gv;                       // gvec bias in C-init
        }
#pragma unroll
        for (int nt = 0; nt < 2; ++nt) {
            const int n = nt * 16 + (l & 15);
#pragma unroll
            for (int ks = 0; ks < 7; ++ks) {
                bf16x8 Bf = *(const bf16x8*)(featB + sw(n, ks * 64 + (l >> 4) * 16));
#pragma unroll
                for (int mt = 0; mt < 2; ++mt)
                    accA[mt][nt] = __builtin_amdgcn_mfma_f32_16x16x32_bf16(
                        A1[mt][ks], Bf, accA[mt][nt], 0, 0, 0);
            }
        }
        bf16x8 A2[2][8];
#pragma unroll
        for (int mt = 0; mt < 2; ++mt) {
            const int omt = (w2 & 1) * 2 + mt;
#pragma unroll
            for (int ks = 0; ks < 8; ++ks)
                A2[mt][ks] = *(const bf16x8*)(W2m +
                    (size_t)((((ch * 4 + ow) * 4 + omt) * 8 + ks) * 64 + l) * 8);
        }
        if (ch) __syncthreads();
#pragma unroll
        for (int mt = 0; mt < 2; ++mt) {
            const int m = w2 * 32 + mt * 16 + ((l >> 4) << 2);
#pragma unroll
            for (int nt = 0; nt < 2; ++nt) {
                const int n = nt * 16 + (l & 15);
                uint2 d;
                d.x = cvt_pk_bf16(lrelu(accA[mt][nt][0]), lrelu(accA[mt][nt][1]));
                d.y = cvt_pk_bf16(lrelu(accA[mt][nt][2]), lrelu(accA[mt][nt][3]));
                *(uint2*)(y1cB + sw(n, m * 2)) = d;
            }
        }
        __syncthreads();
#pragma unroll
        for (int nt = 0; nt < 2; ++nt) {
            const int n = nt * 16 + (l & 15);
#pragma unroll
            for (int ks = 0; ks < 8; ++ks) {
                bf16x8 Bf = *(const bf16x8*)(y1cB + sw(n, ks * 64 + (l >> 4) * 16));
#pragma unroll
                for (int mt = 0; mt < 2; ++mt)
                    accB[mt][nt] = __builtin_amdgcn_mfma_f32_16x16x32_bf16(
                        A2[mt][ks], Bf, accB[mt][nt], 0, 0, 0);
            }
        }
    }

    float p0 = 0.f, p1 = 0.f;
#pragma unroll
    for (int mt = 0; mt < 2; ++mt) {
        const int m = w2 * 32 + mt * 16 + ((l >> 4) << 2);
        const f32x4 bb = *(const f32x4*)(b2v + m);
        const f32x4 w3 = *(const f32x4*)(W3 + m);
#pragma unroll
        for (int r = 0; r < 4; ++r) {
            p0 = fmaf(w3[r], lrelu(accB[mt][0][r] + bb[r]), p0);
            p1 = fmaf(w3[r], lrelu(accB[mt][1][r] + bb[r]), p1);
        }
    }
    p0 += __shfl_xor(p0, 16); p0 += __shfl_xor(p0, 32);
    p1 += __shfl_xor(p1, 16); p1 += __shfl_xor(p1, 32);
    if (l < 16) { red[w2][l] = p0; red[w2][16 + l] = p1; }
    __syncthreads();
    if (t < 32) {
        float s = b3v[0];
#pragma unroll
        for (int ww = 0; ww < 8; ++ww) s += red[ww][t];
        out[(size_t)b * N + n0 + t] = s;
    }
}

extern "C" void kernel_launch(void* const* d_in, const int* in_sizes, int n_in,
                              void* d_out, int out_size, void* d_ws, size_t ws_size,
                              hipStream_t stream) {
    const float* g     = (const float*)d_in[0];
    const float* pts   = (const float*)d_in[1];
    const float* lf    = (const float*)d_in[2];
    const float* W_ef1 = (const float*)d_in[3];
    const float* b_ef1 = (const float*)d_in[4];
    const float* W_ef2 = (const float*)d_in[5];
    const float* b_ef2 = (const float*)d_in[6];
    const float* W1    = (const float*)d_in[7];
    const float* b1    = (const float*)d_in[8];
    const float* W2    = (const float*)d_in[9];
    const float* b2    = (const float*)d_in[10];
    const float* W3    = (const float*)d_in[11];
    const float* b3    = (const float*)d_in[12];
    float* out = (float*)d_out;

    char* ws = (char*)d_ws;
    int*      idx     = (int*)ws;     ws += (size_t)B * N * KTOT * 4;
    float4*   cand4   = (float4*)ws;  ws += (size_t)B * N * 16;
    float4*   cand4s  = (float4*)ws;  ws += (size_t)B * N * 16;
    int*      sortidx = (int*)ws;     ws += (size_t)B * N * 4;
    unsigned* hist    = (unsigned*)ws; ws += (size_t)B * 256 * 4;
    unsigned* boff    = (unsigned*)ws; ws += (size_t)B * 256 * 4;
    float*    topd    = (float*)ws;
    unsigned short* fmax_bf = (unsigned short*)topd;  // alias: topd dead before ef writes fmax
    ws += (size_t)B * NCHW * 16 * N * 4;
    float*    Tbuf  = (float*)ws;    ws += (size_t)B * N * 4;
    float*    gvec  = (float*)ws;    ws += (size_t)B * O1 * 4;
    unsigned short* lfb16 = (unsigned short*)ws; ws += (size_t)B * N * 64 * 2;
    unsigned short* W1p = (unsigned short*)ws; ws += (size_t)S1 * 2;
    unsigned short* W2p = (unsigned short*)ws; ws += (size_t)S2 * 2;
    unsigned short* W1m = (unsigned short*)ws; ws += (size_t)S3 * 2;
    unsigned short* W2m = (unsigned short*)ws; ws += (size_t)S4 * 2;

    hipMemsetAsync(hist, 0, (size_t)B * 256 * 4, stream);
    prep_cand4_hist<<<dim3((B * N) / 256), 256, 0, stream>>>(pts, cand4, hist);
    prep_lf_bf<<<dim3((B * N * 64) / 256), 256, 0, stream>>>(lf, lfb16);
    prepack_all<<<dim3((S1 + S2 + S3 + S4) / 256), 256, 0, stream>>>(
        W_ef1, W_ef2, W1, W2, W1p, W2p, W1m, W2m);
    gvec_kernel<<<dim3(O1 / 4, B), 256, 0, stream>>>(W1, b1, g, gvec);
    knn_prefix<<<dim3(1), 256, 0, stream>>>(hist, boff);
    knn_scatter<<<dim3((B * N) / 256), 256, 0, stream>>>(cand4, boff, cand4s, sortidx);
    knn_pass1w<<<dim3(N / 256, NCHW, B), 256, 0, stream>>>(cand4s, topd);
    knn_thresh<<<dim3(N / 256, B), 256, 0, stream>>>(topd, Tbuf);
    knn_recover<<<dim3(N / 16, B), 256, 0, stream>>>(cand4s, sortidx, Tbuf, boff, idx);
    ef_mlp_mfma<<<dim3(N / 16, B), 256, 0, stream>>>(lfb16, cand4, idx, W1p, b_ef1, W2p, b_ef2, fmax_bf);
    mlp_mfma<<<dim3(N / 32, B), 512, 0, stream>>>(lfb16, pts, fmax_bf, gvec, W1m, W2m, W3, b2, b3, out);
}

// Round 22
// 200.376 us; speedup vs baseline: 1.0664x; 1.0012x over previous
//
#include <hip/hip_runtime.h>
#include <hip/hip_bf16.h>
#include <cstdint>

#define B 2
#define N 8192
#define KTOT 17        // self + 16 neighbors
#define CL 64
#define CEF 67         // CL + 3
#define H1 256
#define H2 128
#define CG 1024
#define O1 1024
#define O2 256
#define NCHW 8               // window chunks
#define WCH 256              // window chunk size (window = 2048)
#define KPAIR 9              // ef: 9 pairs of k-slots (17 -> 18, last duplicated)

typedef unsigned long long u64;
typedef __bf16 bf16x8 __attribute__((ext_vector_type(8)));
typedef float f32x4 __attribute__((ext_vector_type(4)));

__device__ __forceinline__ float lrelu(float v) { return fmaxf(v, 0.01f * v); }

__device__ __forceinline__ unsigned short f2bf(float f) {  // RNE
    union { float f; unsigned u; } v; v.f = f;
    unsigned r = v.u + 0x7FFFu + ((v.u >> 16) & 1u);
    return (unsigned short)(r >> 16);
}

// HW packed f32->bf16 (gfx950): low half = lo, high half = hi
__device__ __forceinline__ unsigned cvt_pk_bf16(float lo, float hi) {
    unsigned r;
    asm("v_cvt_pk_bf16_f32 %0, %1, %2" : "=v"(r) : "v"(lo), "v"(hi));
    return r;
}

__device__ __forceinline__ float norm3(float x, float y, float z) {
    return __fmaf_rn(z, z, __fmaf_rn(y, y, __fmul_rn(x, x)));
}
// d^2-scale key; MUST be byte-identical between pass1w and recover.
__device__ __forceinline__ float dist_key(float qx, float qy, float qz, float qq,
                                          float4 c) {
    float dot = __fmaf_rn(qz, c.z, __fmaf_rn(qy, c.y, __fmul_rn(qx, c.x)));
    float t = __fmaf_rn(-2.f, dot, qq);
    return fmaxf(__fadd_rn(t, c.w), 0.f);
}

__device__ __forceinline__ int nbucket(float nn) {
    return (int)fminf(nn * 16.f, 255.f);
}

// ---------------- fused: pack candidates + norm histogram ----------------
__global__ void prep_cand4_hist(const float* __restrict__ pts, float4* __restrict__ cand4,
                                unsigned* __restrict__ hist) {
    int id = blockIdx.x * 256 + threadIdx.x;       // B*N threads
    int b = id >> 13, j = id & (N - 1);
    const float* px = pts + (size_t)b * 3 * N;
    float x = px[j], y = px[N + j], z = px[2 * N + j];
    float nn = norm3(x, y, z);
    cand4[id] = make_float4(x, y, z, nn);
    atomicAdd(&hist[b * 256 + nbucket(nn)], 1u);
}

__global__ void knn_prefix(const unsigned* __restrict__ hist, unsigned* __restrict__ boff) {
    __shared__ unsigned s[256];
    int t = threadIdx.x;
    for (int b = 0; b < B; ++b) {
        s[t] = hist[b * 256 + t];
        __syncthreads();
        for (int d = 1; d < 256; d <<= 1) {
            unsigned v = (t >= d) ? s[t - d] : 0u;
            __syncthreads();
            s[t] += v;
            __syncthreads();
        }
        boff[b * 256 + t] = s[t] - hist[b * 256 + t];  // exclusive prefix
        __syncthreads();
    }
}
__global__ void knn_scatter(const float4* __restrict__ cand4, unsigned* __restrict__ boff,
                            float4* __restrict__ cand4s, int* __restrict__ sortidx) {
    int id = blockIdx.x * 256 + threadIdx.x;
    int b = id >> 13, j = id & (N - 1);
    float4 c = cand4[id];
    unsigned pos = atomicAdd(&boff[b * 256 + nbucket(c.w)], 1u);
    cand4s[(size_t)b * N + pos] = c;
    sortidx[b * N + pos] = j;
}
// NOTE: after knn_scatter, boff[b*256+k] == INCLUSIVE prefix (end of bucket k).

// ---------------- fused prepack: all 4 weight tensors in one dispatch ----------------
#define S1 24576            // ef W1 frags
#define S2 32768            // ef W2 frags
#define S3 229376           // mlp W1 frags
#define S4 262144           // mlp W2 frags
__global__ void prepack_all(const float* __restrict__ W_ef1, const float* __restrict__ W_ef2,
                            const float* __restrict__ W1, const float* __restrict__ W2,
                            unsigned short* __restrict__ W1p, unsigned short* __restrict__ W2p,
                            unsigned short* __restrict__ W1m, unsigned short* __restrict__ W2m) {
    int id = blockIdx.x * 256 + threadIdx.x;
    if (id < S1) {
        int j = id & 7, l = (id >> 3) & 63, rest = id >> 9;
        int ks = rest % 3, mt = rest / 3;
        int m = mt * 16 + (l & 15);
        int k = ks * 32 + ((l >> 4) << 3) + j;
        W1p[id] = f2bf((k < CEF) ? W_ef1[m * CEF + k] : 0.f);
        return;
    }
    id -= S1;
    if (id < S2) {
        int j = id & 7, l = (id >> 3) & 63, rest = id >> 9;
        int ks = rest & 7, mt = rest >> 3;
        int m = mt * 16 + (l & 15);
        int k = ks * 32 + ((l >> 4) << 3) + j;
        W2p[id] = f2bf(W_ef2[m * H1 + k]);
        return;
    }
    id -= S2;
    if (id < S3) {
        int j = id & 7, l = (id >> 3) & 63, rest = id >> 9;
        int ks = rest % 7; int rest2 = rest / 7;
        int mt = rest2 & 3, w = (rest2 >> 2) & 3, ch = rest2 >> 4;
        int m = ch * 256 + w * 64 + mt * 16 + (l & 15);
        int k = ks * 32 + ((l >> 4) << 3) + j;
        W1m[id] = (k < 195) ? f2bf(W1[(size_t)m * 1219 + 1024 + k]) : (unsigned short)0;
        return;
    }
    id -= S3;
    if (id < S4) {
        int j = id & 7, l = (id >> 3) & 63, rest = id >> 9;
        int ks = rest & 7; int rest2 = rest >> 3;
        int mt = rest2 & 3, w = (rest2 >> 2) & 3, ch = rest2 >> 4;
        int m = w * 64 + mt * 16 + (l & 15);
        int k = ch * 256 + ks * 32 + ((l >> 4) << 3) + j;
        W2m[id] = f2bf(W2[(size_t)m * 1024 + k]);
    }
}

// ---------------- prep lf to point-major bf16 ----------------
__global__ void prep_lf_bf(const float* __restrict__ lf, unsigned short* __restrict__ out) {
    int id = blockIdx.x * 256 + threadIdx.x;       // B*N*64 threads
    int c = id & 63;
    int n = (id >> 6) & (N - 1);
    int b = id >> 19;
    out[id] = f2bf(lf[((size_t)b * CL + c) * N + n]);
}

// ---------------- gvec: one wave per output row, shuffle reduce ----------------
__global__ __launch_bounds__(256) void gvec_kernel(const float* __restrict__ W1,
                                                   const float* __restrict__ b1,
                                                   const float* __restrict__ g,
                                                   float* __restrict__ gvec) {
    const int t = threadIdx.x;
    const int l = t & 63;
    const int o = blockIdx.x * 4 + (t >> 6);   // 0..1023
    const int b = blockIdx.y;
    const float* row = W1 + (size_t)o * 1219;
    const float* gb = g + b * CG;
    float s = 0.f;
#pragma unroll
    for (int i = 0; i < CG / 64; ++i)
        s = fmaf(row[l + i * 64], gb[l + i * 64], s);
    s += __shfl_xor(s, 1);  s += __shfl_xor(s, 2);  s += __shfl_xor(s, 4);
    s += __shfl_xor(s, 8);  s += __shfl_xor(s, 16); s += __shfl_xor(s, 32);
    if (l == 0) gvec[b * O1 + o] = s + b1[o];
}

// ---------------- KNN pass1w: top-16 over 2048 norm-window (8 chunks x 256) ----------------
__global__ __launch_bounds__(256) void knn_pass1w(const float4* __restrict__ cand4s,
                                                  float* __restrict__ topd) {
    const int t = threadIdx.x;
    const int x = blockIdx.x;       // query block (sorted positions x*256..+256)
    const int chunk = blockIdx.y;   // 0..7
    const int b = blockIdx.z;
    int wstart = x * 256 - 896;
    wstart = wstart < 0 ? 0 : (wstart > N - 2048 ? N - 2048 : wstart);
    const int p = x * 256 + t;                  // sorted position of query
    const int rel = p - wstart - chunk * WCH;   // self slot in this chunk (may be OOR)
    const float4 q = cand4s[(size_t)b * N + p];
    const float qq = q.w;
    const float4* cb = cand4s + (size_t)b * N + wstart + chunk * WCH;
    float qd[16];
#pragma unroll
    for (int r = 0; r < 16; ++r) qd[r] = __builtin_inff();
#pragma unroll 8
    for (int s = 0; s < WCH; ++s) {
        float key = dist_key(q.x, q.y, q.z, qq, cb[s]);
        if (s == rel) key = __builtin_inff();   // exclude self
#pragma unroll
        for (int r = 15; r >= 1; --r)
            qd[r] = __builtin_amdgcn_fmed3f(key, qd[r - 1], qd[r]);
        qd[0] = fminf(key, qd[0]);
    }
#pragma unroll
    for (int s = 0; s < 16; ++s)
        topd[(size_t)((b * NCHW + chunk) * 16 + s) * N + p] = qd[s];
}

// ---------------- KNN thresh: merge 8 window lists -> T' (position-indexed) ----------------
__global__ __launch_bounds__(256) void knn_thresh(const float* __restrict__ topd,
                                                  float* __restrict__ Tbuf) {
    const int t = threadIdx.x;
    const int i = blockIdx.x * 256 + t;   // sorted position
    const int b = blockIdx.y;
    float qd[16];
#pragma unroll
    for (int s = 0; s < 16; ++s)
        qd[s] = topd[(size_t)((b * NCHW + 0) * 16 + s) * N + i];
    for (int c = 1; c < NCHW; ++c) {
        for (int s = 0; s < 16; ++s) {
            float pk = topd[(size_t)((b * NCHW + c) * 16 + s) * N + i];
            if (pk >= qd[15]) break;  // sorted: rest of chunk also fails
#pragma unroll
            for (int r = 15; r >= 1; --r)
                qd[r] = __builtin_amdgcn_fmed3f(pk, qd[r - 1], qd[r]);
            qd[0] = fminf(pk, qd[0]);
        }
    }
    Tbuf[b * N + i] = qd[15];
}

// ---------------- KNN recover: norm-windowed scan (4x unrolled), exact rank-select 16 ----------------
__global__ __launch_bounds__(256) void knn_recover(const float4* __restrict__ cand4s,
                                                   const int* __restrict__ sortidx,
                                                   const float* __restrict__ Tbuf,
                                                   const unsigned* __restrict__ boff,
                                                   int* __restrict__ idx) {
    const int t = threadIdx.x;
    const int lg = t & 15;
    const int grp = t >> 4;
    const int b = blockIdx.y;
    const int pq = blockIdx.x * 16 + grp;      // sorted position
    __shared__ u64 cbuf[16][64];
    __shared__ unsigned obuf[16][17];
    __shared__ int scnt[16];
    if (lg == 0) scnt[grp] = 0;
    __syncthreads();
    const int gq = sortidx[b * N + pq];
    const float4 q = cand4s[(size_t)b * N + pq];
    const float qq = q.w;
    const float T = Tbuf[b * N + pq];
    const float nq = sqrtf(qq);
    const float r = sqrtf(T) * 1.001f + 0.01f;
    const float lov = (nq > r) ? (nq - r) * (nq - r) : 0.f;
    const float hiv = (nq + r) * (nq + r);
    const int lob = nbucket(lov), hib = nbucket(hiv);
    const int start = (lob == 0) ? 0 : (int)boff[b * 256 + lob - 1];
    const int end = (int)boff[b * 256 + hib];
    const float4* cs = cand4s + (size_t)b * N;
    const int* si = sortidx + b * N;
    const int last = end - 1;
    for (int pos = start + lg; pos < end; pos += 64) {
        int p1 = pos + 16, p2 = pos + 32, p3 = pos + 48;
        float4 c0 = cs[pos];
        float4 c1 = cs[p1 < end ? p1 : last];
        float4 c2 = cs[p2 < end ? p2 : last];
        float4 c3 = cs[p3 < end ? p3 : last];
        float k0 = dist_key(q.x, q.y, q.z, qq, c0);
        float k1 = dist_key(q.x, q.y, q.z, qq, c1);
        float k2 = dist_key(q.x, q.y, q.z, qq, c2);
        float k3 = dist_key(q.x, q.y, q.z, qq, c3);
        if (k0 <= T) {
            int j = si[pos];
            if (j != gq) { int p = atomicAdd(&scnt[grp], 1); if (p < 64) cbuf[grp][p] = ((u64)__float_as_uint(k0) << 32) | (unsigned)j; }
        }
        if (k1 <= T && p1 < end) {
            int j = si[p1];
            if (j != gq) { int p = atomicAdd(&scnt[grp], 1); if (p < 64) cbuf[grp][p] = ((u64)__float_as_uint(k1) << 32) | (unsigned)j; }
        }
        if (k2 <= T && p2 < end) {
            int j = si[p2];
            if (j != gq) { int p = atomicAdd(&scnt[grp], 1); if (p < 64) cbuf[grp][p] = ((u64)__float_as_uint(k2) << 32) | (unsigned)j; }
        }
        if (k3 <= T && p3 < end) {
            int j = si[p3];
            if (j != gq) { int p = atomicAdd(&scnt[grp], 1); if (p < 64) cbuf[grp][p] = ((u64)__float_as_uint(k3) << 32) | (unsigned)j; }
        }
    }
    __syncthreads();
    int cnt = scnt[grp]; if (cnt > 64) cnt = 64;
    // rank selection over (keybits, idx) packs: exact top-16, lowest-index ties
    u64 mine[4]; bool have[4]; int rank[4];
#pragma unroll
    for (int e = 0; e < 4; ++e) {
        int pi = lg + e * 16;
        have[e] = pi < cnt;
        mine[e] = have[e] ? cbuf[grp][pi] : ~0ull;
        rank[e] = 0;
    }
    for (int m = 0; m < cnt; ++m) {
        u64 v = cbuf[grp][m];
#pragma unroll
        for (int e = 0; e < 4; ++e) rank[e] += (v < mine[e]) ? 1 : 0;
    }
    obuf[grp][1 + lg] = (unsigned)gq;   // defensive fill
    __syncthreads();
#pragma unroll
    for (int e = 0; e < 4; ++e)
        if (have[e] && rank[e] < 16)
            obuf[grp][1 + rank[e]] = (unsigned)(mine[e] & 0xFFFFFFFFu);
    if (lg == 0) obuf[grp][0] = (unsigned)gq;
    __syncthreads();
    int* op = idx + (size_t)(b * N + gq) * KTOT;
    op[lg] = (int)obuf[grp][lg];
    if (lg == 0) op[16] = (int)obuf[grp][16];
}

// ---------------- fused edge MLP via MFMA: 2 k-slots/iter, point-major bf16 gather ----------------
// (R17-proven version: f_lds staging + register prefetch, 2 barriers/iter)
__global__ __launch_bounds__(256) void ef_mlp_mfma(
        const unsigned short* __restrict__ lfb16, const float4* __restrict__ cand4,
        const int* __restrict__ idx,
        const unsigned short* __restrict__ W1p, const float* __restrict__ b_ef1,
        const unsigned short* __restrict__ W2p, const float* __restrict__ b_ef2,
        unsigned short* __restrict__ fmax_bf) {
    const int t = threadIdx.x;
    const int w = t >> 6;       // wave 0..3
    const int l = t & 63;
    const int n0 = blockIdx.x * 16;
    const int b = blockIdx.y;

    __shared__ unsigned short f_lds[32][104];   // [slot*16+p][c 0..95]
    __shared__ unsigned short h1_lds[32][264];  // [slot*16+p][m]
    __shared__ int idx_l[16][17];

    for (int e = t; e < 16 * 17; e += 256) {
        int p = e / 17, k = e - p * 17;
        idx_l[p][k] = idx[(size_t)(b * N + n0 + p) * KTOT + k];
    }
    for (int e = t; e < 32 * 29; e += 256) {    // zero rows 67..95 once
        int col = e / 29, rr = 67 + e % 29;
        f_lds[col][rr] = 0;
    }

    f32x4 b1i[4];   // GEMM1 bias as acc init
#pragma unroll
    for (int mt = 0; mt < 4; ++mt)
#pragma unroll
        for (int r = 0; r < 4; ++r)
            b1i[mt][r] = b_ef1[(w * 4 + mt) * 16 + ((l >> 4) << 2) + r];
    f32x4 b2i[2];   // GEMM2 bias as acc init
#pragma unroll
    for (int i = 0; i < 2; ++i)
#pragma unroll
        for (int r = 0; r < 4; ++r)
            b2i[i][r] = b_ef2[(w * 2 + i) * 16 + ((l >> 4) << 2) + r];

    bf16x8 A1[12];
#pragma unroll
    for (int mt = 0; mt < 4; ++mt)
#pragma unroll
        for (int ks = 0; ks < 3; ++ks)
            A1[mt * 3 + ks] = *(const bf16x8*)(W1p + (size_t)(((w * 4 + mt) * 3 + ks) * 64 + l) * 8);
    bf16x8 A2[16];
#pragma unroll
    for (int i = 0; i < 2; ++i)
#pragma unroll
        for (int ks = 0; ks < 8; ++ks)
            A2[i * 8 + ks] = *(const bf16x8*)(W2p + (size_t)(((w * 2 + i) * 8 + ks) * 64 + l) * 8);

    const int p_my = t >> 4;
    const int cbr = (t & 15) * 4;               // channel base (4 channels/thread)
    const unsigned short* lfb = lfb16 + (size_t)b * N * 64;
    const float4* cand4b = cand4 + (size_t)b * N;
    float selfp = 0.f;
    if (t < 48) selfp = ((const float*)(cand4b + n0 + (t & 15)))[t >> 4];

    __syncthreads();  // idx_l + zero rows visible

    uint2 rbf[2];     // 2 slots x 4 bf16 channels (pre-converted)
    float rp[2];      // xyz gather (t<48)
    auto prefetch = [&](int g) {
#pragma unroll
        for (int sl = 0; sl < 2; ++sl) {
            int kk = 2 * g + sl; if (kk > 16) kk = 16;
            int j = idx_l[p_my][kk];
            rbf[sl] = *(const uint2*)(lfb + (size_t)j * 64 + cbr);
        }
        if (t < 48) {
#pragma unroll
            for (int sl = 0; sl < 2; ++sl) {
                int kk = 2 * g + sl; if (kk > 16) kk = 16;
                int j = idx_l[t & 15][kk];
                rp[sl] = ((const float*)(cand4b + j))[t >> 4];
            }
        }
    };
    auto commit = [&](int g) {
#pragma unroll
        for (int sl = 0; sl < 2; ++sl)
            *(uint2*)&f_lds[sl * 16 + p_my][cbr] = rbf[sl];   // raw copy, no cvt
        if (t < 48) {
#pragma unroll
            for (int sl = 0; sl < 2; ++sl) {
                int kk = 2 * g + sl; if (kk > 16) kk = 16;
                float v = (kk == 0) ? selfp : selfp - rp[sl];
                f_lds[sl * 16 + (t & 15)][64 + (t >> 4)] = f2bf(v);
            }
        }
    };

    prefetch(0);
    f32x4 rmax[2];
#pragma unroll
    for (int i = 0; i < 2; ++i)
#pragma unroll
        for (int r = 0; r < 4; ++r) rmax[i][r] = -1e30f;

    for (int g = 0; g < KPAIR; ++g) {
        commit(g);
        __syncthreads();                 // A: f(g) ready; prev GEMM2 h1-reads done
        if (g < KPAIR - 1) prefetch(g + 1);
        f32x4 acc1[4][2];
#pragma unroll
        for (int mt = 0; mt < 4; ++mt)
#pragma unroll
            for (int nt = 0; nt < 2; ++nt) acc1[mt][nt] = b1i[mt];   // bias in C-init
#pragma unroll
        for (int nt = 0; nt < 2; ++nt) {
            const int col = nt * 16 + (l & 15);
            bf16x8 Bf0 = *(const bf16x8*)&f_lds[col][(l >> 4) * 8];
            bf16x8 Bf1 = *(const bf16x8*)&f_lds[col][32 + (l >> 4) * 8];
            bf16x8 Bf2 = *(const bf16x8*)&f_lds[col][64 + (l >> 4) * 8];
#pragma unroll
            for (int mt = 0; mt < 4; ++mt) {
                acc1[mt][nt] = __builtin_amdgcn_mfma_f32_16x16x32_bf16(A1[mt * 3 + 0], Bf0, acc1[mt][nt], 0, 0, 0);
                acc1[mt][nt] = __builtin_amdgcn_mfma_f32_16x16x32_bf16(A1[mt * 3 + 1], Bf1, acc1[mt][nt], 0, 0, 0);
                acc1[mt][nt] = __builtin_amdgcn_mfma_f32_16x16x32_bf16(A1[mt * 3 + 2], Bf2, acc1[mt][nt], 0, 0, 0);
            }
        }
#pragma unroll
        for (int mt = 0; mt < 4; ++mt)
#pragma unroll
            for (int nt = 0; nt < 2; ++nt) {
                uint2 d;
                d.x = cvt_pk_bf16(lrelu(acc1[mt][nt][0]), lrelu(acc1[mt][nt][1]));
                d.y = cvt_pk_bf16(lrelu(acc1[mt][nt][2]), lrelu(acc1[mt][nt][3]));
                *(uint2*)&h1_lds[nt * 16 + (l & 15)][(w * 4 + mt) * 16 + ((l >> 4) << 2)] = d;
            }
        __syncthreads();                 // B: h1(g) ready; all f(g)-reads done
        f32x4 acc2[2][2];
#pragma unroll
        for (int i = 0; i < 2; ++i)
#pragma unroll
            for (int nt = 0; nt < 2; ++nt) acc2[i][nt] = b2i[i];     // bias in C-init
#pragma unroll
        for (int nt = 0; nt < 2; ++nt) {
            const int col = nt * 16 + (l & 15);
#pragma unroll
            for (int ks = 0; ks < 8; ++ks) {
                bf16x8 Bf = *(const bf16x8*)&h1_lds[col][ks * 32 + (l >> 4) * 8];
                acc2[0][nt] = __builtin_amdgcn_mfma_f32_16x16x32_bf16(A2[0 * 8 + ks], Bf, acc2[0][nt], 0, 0, 0);
                acc2[1][nt] = __builtin_amdgcn_mfma_f32_16x16x32_bf16(A2[1 * 8 + ks], Bf, acc2[1][nt], 0, 0, 0);
            }
        }
#pragma unroll
        for (int i = 0; i < 2; ++i)
#pragma unroll
            for (int nt = 0; nt < 2; ++nt)
#pragma unroll
                for (int r = 0; r < 4; ++r)
                    rmax[i][r] = fmaxf(rmax[i][r], acc2[i][nt][r]);
    }
    // bias already folded into acc2 -> rmax; store bf16
    const size_t nbase = ((size_t)(b * N + n0 + (l & 15))) * H2;
#pragma unroll
    for (int i = 0; i < 2; ++i) {
        uint2 d;
        d.x = cvt_pk_bf16(rmax[i][0], rmax[i][1]);
        d.y = cvt_pk_bf16(rmax[i][2], rmax[i][3]);
        *(uint2*)&fmax_bf[nbase + (w * 2 + i) * 16 + ((l >> 4) << 2)] = d;
    }
}

// ---------------- fused final MLP via MFMA: 8 waves, halved per-wave tile ----------------
__global__ __launch_bounds__(512) void mlp_mfma(
        const unsigned short* __restrict__ lfb16, const float* __restrict__ pts,
        const unsigned short* __restrict__ fmax_bf, const float* __restrict__ gvec,
        const unsigned short* __restrict__ W1m, const unsigned short* __restrict__ W2m,
        const float* __restrict__ W3, const float* __restrict__ b2v,
        const float* __restrict__ b3v, float* __restrict__ out) {
    const int t = threadIdx.x;
    const int w2 = t >> 6;          // wave 0..7
    const int l = t & 63;
    const int ow = w2 >> 1;         // old wave coord in prepacked layout
    const int n0 = blockIdx.x * 32;
    const int b = blockIdx.y;

    __shared__ unsigned short feat_s[32 * 256];   // [n][256], swizzled
    __shared__ unsigned short y1c_s[32 * 256];    // [n][256], swizzled
    __shared__ float red[8][32];

    auto sw = [](int n, int cbyte) -> unsigned {
        return (unsigned)(n << 9) | ((unsigned)cbyte ^ (((unsigned)n & 7u) << 4));
    };
    char* featB = (char*)feat_s;
    char* y1cB = (char*)y1c_s;

    const unsigned short* lfb = lfb16 + (size_t)b * N * 64;
    for (int e = t; e < 32 * 64; e += 512) {       // local feats (bf16, raw copy)
        int c = e & 63, n = e >> 6;
        *(unsigned short*)(featB + sw(n, c * 2)) = lfb[(size_t)(n0 + n) * 64 + c];
    }
    for (int e = t; e < 32 * 128; e += 512) {      // fmax (bf16, raw copy)
        int c = e & 127, n = e >> 7;
        *(unsigned short*)(featB + sw(n, (64 + c) * 2)) =
            fmax_bf[((size_t)(b * N + n0 + n)) * H2 + c];
    }
    if (t < 96) {                                   // xyz
        int n = t & 31, d = t >> 5;
        *(unsigned short*)(featB + sw(n, (192 + d) * 2)) =
            f2bf(pts[((size_t)(b * 3 + d)) * N + n0 + n]);
    }
    for (int e = t; e < 32 * 29; e += 512) {       // zero pad k=195..223
        int n = e / 29, c = 195 + e % 29;
        *(unsigned short*)(featB + sw(n, c * 2)) = 0;
    }
    __syncthreads();

    f32x4 accB[2][2];
#pragma unroll
    for (int mt = 0; mt < 2; ++mt)
#pragma unroll
        for (int nt = 0; nt < 2; ++nt)
            accB[mt][nt] = (f32x4){0.f, 0.f, 0.f, 0.f};

    for (int ch = 0; ch < 4; ++ch) {
        bf16x8 A1[2][7];
#pragma unroll
        for (int mt = 0; mt < 2; ++mt) {
            const int omt = (w2 & 1) * 2 + mt;
#pragma unroll
            for (int ks = 0; ks < 7; ++ks)
                A1[mt][ks] = *(const bf16x8*)(W1m +
                    (size_t)((((ch * 4 + ow) * 4 + omt) * 7 + ks) * 64 + l) * 8);
        }
        f32x4 accA[2][2];
#pragma unroll
        for (int mt = 0; mt < 2; ++mt) {
            const int m = w2 * 32 + mt * 16 + ((l >> 4) << 2);
            const f32x4 gv = *(const f32x4*)(gvec + b * O1 + ch * 256 + m);
#pragma unroll
            for (int nt = 0; nt < 2; ++nt)
                accA[mt][nt] = gv;                       // gvec bias in C-init
        }
#pragma unroll
        for (int nt = 0; nt < 2; ++nt) {
            const int n = nt * 16 + (l & 15);
#pragma unroll
            for (int ks = 0; ks < 7; ++ks) {
                bf16x8 Bf = *(const bf16x8*)(featB + sw(n, ks * 64 + (l >> 4) * 16));
#pragma unroll
                for (int mt = 0; mt < 2; ++mt)
                    accA[mt][nt] = __builtin_amdgcn_mfma_f32_16x16x32_bf16(
                        A1[mt][ks], Bf, accA[mt][nt], 0, 0, 0);
            }
        }
        bf16x8 A2[2][8];
#pragma unroll
        for (int mt = 0; mt < 2; ++mt) {
            const int omt = (w2 & 1) * 2 + mt;
#pragma unroll
            for (int ks = 0; ks < 8; ++ks)
                A2[mt][ks] = *(const bf16x8*)(W2m +
                    (size_t)((((ch * 4 + ow) * 4 + omt) * 8 + ks) * 64 + l) * 8);
        }
        if (ch) __syncthreads();
#pragma unroll
        for (int mt = 0; mt < 2; ++mt) {
            const int m = w2 * 32 + mt * 16 + ((l >> 4) << 2);
#pragma unroll
            for (int nt = 0; nt < 2; ++nt) {
                const int n = nt * 16 + (l & 15);
                uint2 d;
                d.x = cvt_pk_bf16(lrelu(accA[mt][nt][0]), lrelu(accA[mt][nt][1]));
                d.y = cvt_pk_bf16(lrelu(accA[mt][nt][2]), lrelu(accA[mt][nt][3]));
                *(uint2*)(y1cB + sw(n, m * 2)) = d;
            }
        }
        __syncthreads();
#pragma unroll
        for (int nt = 0; nt < 2; ++nt) {
            const int n = nt * 16 + (l & 15);
#pragma unroll
            for (int ks = 0; ks < 8; ++ks) {
                bf16x8 Bf = *(const bf16x8*)(y1cB + sw(n, ks * 64 + (l >> 4) * 16));
#pragma unroll
                for (int mt = 0; mt < 2; ++mt)
                    accB[mt][nt] = __builtin_amdgcn_mfma_f32_16x16x32_bf16(
                        A2[mt][ks], Bf, accB[mt][nt], 0, 0, 0);
            }
        }
    }

    float p0 = 0.f, p1 = 0.f;
#pragma unroll
    for (int mt = 0; mt < 2; ++mt) {
        const int m = w2 * 32 + mt * 16 + ((l >> 4) << 2);
        const f32x4 bb = *(const f32x4*)(b2v + m);
        const f32x4 w3 = *(const f32x4*)(W3 + m);
#pragma unroll
        for (int r = 0; r < 4; ++r) {
            p0 = fmaf(w3[r], lrelu(accB[mt][0][r] + bb[r]), p0);
            p1 = fmaf(w3[r], lrelu(accB[mt][1][r] + bb[r]), p1);
        }
    }
    p0 += __shfl_xor(p0, 16); p0 += __shfl_xor(p0, 32);
    p1 += __shfl_xor(p1, 16); p1 += __shfl_xor(p1, 32);
    if (l < 16) { red[w2][l] = p0; red[w2][16 + l] = p1; }
    __syncthreads();
    if (t < 32) {
        float s = b3v[0];
#pragma unroll
        for (int ww = 0; ww < 8; ++ww) s += red[ww][t];
        out[(size_t)b * N + n0 + t] = s;
    }
}

extern "C" void kernel_launch(void* const* d_in, const int* in_sizes, int n_in,
                              void* d_out, int out_size, void* d_ws, size_t ws_size,
                              hipStream_t stream) {
    const float* g     = (const float*)d_in[0];
    const float* pts   = (const float*)d_in[1];
    const float* lf    = (const float*)d_in[2];
    const float* W_ef1 = (const float*)d_in[3];
    const float* b_ef1 = (const float*)d_in[4];
    const float* W_ef2 = (const float*)d_in[5];
    const float* b_ef2 = (const float*)d_in[6];
    const float* W1    = (const float*)d_in[7];
    const float* b1    = (const float*)d_in[8];
    const float* W2    = (const float*)d_in[9];
    const float* b2    = (const float*)d_in[10];
    const float* W3    = (const float*)d_in[11];
    const float* b3    = (const float*)d_in[12];
    float* out = (float*)d_out;

    char* ws = (char*)d_ws;
    int*      idx     = (int*)ws;     ws += (size_t)B * N * KTOT * 4;
    float4*   cand4   = (float4*)ws;  ws += (size_t)B * N * 16;
    float4*   cand4s  = (float4*)ws;  ws += (size_t)B * N * 16;
    int*      sortidx = (int*)ws;     ws += (size_t)B * N * 4;
    unsigned* hist    = (unsigned*)ws; ws += (size_t)B * 256 * 4;
    unsigned* boff    = (unsigned*)ws; ws += (size_t)B * 256 * 4;
    float*    topd    = (float*)ws;
    unsigned short* fmax_bf = (unsigned short*)topd;  // alias: topd dead before ef writes fmax
    ws += (size_t)B * NCHW * 16 * N * 4;
    float*    Tbuf  = (float*)ws;    ws += (size_t)B * N * 4;
    float*    gvec  = (float*)ws;    ws += (size_t)B * O1 * 4;
    unsigned short* lfb16 = (unsigned short*)ws; ws += (size_t)B * N * 64 * 2;
    unsigned short* W1p = (unsigned short*)ws; ws += (size_t)S1 * 2;
    unsigned short* W2p = (unsigned short*)ws; ws += (size_t)S2 * 2;
    unsigned short* W1m = (unsigned short*)ws; ws += (size_t)S3 * 2;
    unsigned short* W2m = (unsigned short*)ws; ws += (size_t)S4 * 2;

    hipMemsetAsync(hist, 0, (size_t)B * 256 * 4, stream);
    prep_cand4_hist<<<dim3((B * N) / 256), 256, 0, stream>>>(pts, cand4, hist);
    prep_lf_bf<<<dim3((B * N * 64) / 256), 256, 0, stream>>>(lf, lfb16);
    prepack_all<<<dim3((S1 + S2 + S3 + S4) / 256), 256, 0, stream>>>(
        W_ef1, W_ef2, W1, W2, W1p, W2p, W1m, W2m);
    gvec_kernel<<<dim3(O1 / 4, B), 256, 0, stream>>>(W1, b1, g, gvec);
    knn_prefix<<<dim3(1), 256, 0, stream>>>(hist, boff);
    knn_scatter<<<dim3((B * N) / 256), 256, 0, stream>>>(cand4, boff, cand4s, sortidx);
    knn_pass1w<<<dim3(N / 256, NCHW, B), 256, 0, stream>>>(cand4s, topd);
    knn_thresh<<<dim3(N / 256, B), 256, 0, stream>>>(topd, Tbuf);
    knn_recover<<<dim3(N / 16, B), 256, 0, stream>>>(cand4s, sortidx, Tbuf, boff, idx);
    ef_mlp_mfma<<<dim3(N / 16, B), 256, 0, stream>>>(lfb16, cand4, idx, W1p, b_ef1, W2p, b_ef2, fmax_bf);
    mlp_mfma<<<dim3(N / 32, B), 512, 0, stream>>>(lfb16, pts, fmax_bf, gvec, W1m, W2m, W3, b2, b3, out);
}